// Round 1
// 556.241 us; speedup vs baseline: 1.0795x; 1.0795x over previous
//
#include <hip/hip_runtime.h>
#include <math.h>

#define WDIM 256
#define HW   65536

struct cplx { float x, y; };
__device__ __forceinline__ cplx cmul(cplx a, cplx b){ return {a.x*b.x - a.y*b.y, a.x*b.y + a.y*b.x}; }
__device__ __forceinline__ cplx cadd(cplx a, cplx b){ return {a.x+b.x, a.y+b.y}; }
__device__ __forceinline__ cplx csub(cplx a, cplx b){ return {a.x-b.x, a.y-b.y}; }
__device__ __forceinline__ void swapc(cplx& a, cplx& b){ cplx t=a; a=b; b=t; }

typedef __attribute__((ext_vector_type(8))) short short8;
typedef __attribute__((ext_vector_type(4))) float float4v;

__device__ __forceinline__ unsigned short f2bf(float f){
  unsigned int u = __float_as_uint(f);
  unsigned int r = (u + 0x7FFFu + ((u >> 16) & 1u)) >> 16;
  return (unsigned short)r;
}
__device__ __forceinline__ float bf2f(unsigned short h){
  return __uint_as_float(((unsigned int)h) << 16);
}

// ---------------- 16-point FFT in registers (radix-2 DIT, bit-reversed input) ----
template<bool INV>
__device__ __forceinline__ void fft16(cplx v[16]) {
  const float C16[8] = {1.f, 0.9238795325112867f, 0.7071067811865476f, 0.3826834323650898f,
                        0.f, -0.3826834323650898f, -0.7071067811865476f, -0.9238795325112867f};
  const float S16[8] = {0.f, 0.3826834323650898f, 0.7071067811865476f, 0.9238795325112867f,
                        1.f, 0.9238795325112867f, 0.7071067811865476f, 0.3826834323650898f};
  swapc(v[1], v[8]); swapc(v[2], v[4]); swapc(v[3], v[12]);
  swapc(v[5], v[10]); swapc(v[7], v[14]); swapc(v[11], v[13]);
  #pragma unroll
  for (int s = 1; s <= 4; ++s) {
    const int m = 1 << s, half = m >> 1, step = 16 >> s;
    #pragma unroll
    for (int k = 0; k < 16; k += m) {
      #pragma unroll
      for (int j = 0; j < half; ++j) {
        cplx w = {C16[j*step], INV ? S16[j*step] : -S16[j*step]};
        cplx t = cmul(w, v[k+j+half]);
        v[k+j+half] = csub(v[k+j], t);
        v[k+j]      = cadd(v[k+j], t);
      }
    }
  }
}

template<bool INV>
__device__ void fft256_16(cplx v[16], int t, cplx* Yu) {
  fft16<INV>(v);
  float ang = (INV ? 6.283185307179586f : -6.283185307179586f) * (float)t * (1.0f/256.0f);
  float sn, cs; sincosf(ang, &sn, &cs);
  cplx wstep = {cs, sn}, w = {1.f, 0.f};
  #pragma unroll
  for (int c = 0; c < 16; ++c) { v[c] = cmul(v[c], w); w = cmul(w, wstep); }
  __syncthreads();
  #pragma unroll
  for (int c = 0; c < 16; ++c) Yu[t*17 + c] = v[c];
  __syncthreads();
  cplx z[16];
  #pragma unroll
  for (int b = 0; b < 16; ++b) z[b] = Yu[b*17 + t];
  fft16<INV>(z);
  #pragma unroll
  for (int d = 0; d < 16; ++d) v[d] = z[d];
  __syncthreads();
}

// ---------------- row FFT kernels -------------------------------------------
// small path: real a-b -> row FFT (one plane per blockIdx.y)
__global__ __launch_bounds__(256) void k_row_fwd_sub(const float* __restrict__ a,
                                                     const float* __restrict__ b,
                                                     cplx* __restrict__ out) {
  __shared__ cplx Y[16*280];
  int unit = threadIdx.x >> 4, t = threadIdx.x & 15;
  size_t base = (size_t)blockIdx.y*HW + (size_t)(blockIdx.x*16 + unit)*WDIM;
  cplx v[16];
  #pragma unroll
  for (int i = 0; i < 16; ++i) { size_t idx = base + i*16 + t; v[i] = {a[idx] - b[idx], 0.f}; }
  fft256_16<false>(v, t, Y + unit*280);
  #pragma unroll
  for (int d = 0; d < 16; ++d) out[base + t + 16*d] = v[d];
}

// packed path: planes (2p, 2p+1) of (a-b) as re+i*im; blockIdx.y = b*16+p
__global__ __launch_bounds__(256) void k_row_fwd_sub_p(const float* __restrict__ a,
                                                       const float* __restrict__ b,
                                                       cplx* __restrict__ out) {
  __shared__ cplx Y[16*280];
  int unit = threadIdx.x >> 4, t = threadIdx.x & 15;
  int bp = blockIdx.y; int bb = bp >> 4, p = bp & 15;
  size_t rowoff = (size_t)(blockIdx.x*16 + unit)*WDIM;
  size_t base0 = ((size_t)(bb*32 + 2*p))*HW + rowoff;
  size_t base1 = base0 + HW;
  size_t baseo = (size_t)bp*HW + rowoff;
  cplx v[16];
  #pragma unroll
  for (int i = 0; i < 16; ++i) {
    size_t o = i*16 + t;
    v[i] = {a[base0+o] - b[base0+o], a[base1+o] - b[base1+o]};
  }
  fft256_16<false>(v, t, Y + unit*280);
  #pragma unroll
  for (int d = 0; d < 16; ++d) out[baseo + t + 16*d] = v[d];
}

__global__ __launch_bounds__(256) void k_row_inv(const cplx* __restrict__ in,
                                                 cplx* __restrict__ out) {
  __shared__ cplx Y[16*280];
  int unit = threadIdx.x >> 4, t = threadIdx.x & 15;
  size_t base = (size_t)blockIdx.y*HW + (size_t)(blockIdx.x*16 + unit)*WDIM;
  cplx v[16];
  #pragma unroll
  for (int i = 0; i < 16; ++i) v[i] = in[base + i*16 + t];
  fft256_16<true>(v, t, Y + unit*280);
  #pragma unroll
  for (int d = 0; d < 16; ++d) out[base + t + 16*d] = {v[d].x*(1.f/256.f), v[d].y*(1.f/256.f)};
}

// ---------------- column FFT core -------------------------------------------
template<bool INV>
__device__ void col_core(const cplx* __restrict__ in, cplx* lds, cplx v[16], size_t planeBase) {
  int tid = threadIdx.x;
  #pragma unroll
  for (int i = 0; i < 16; ++i) {
    int idx = tid + 256*i; int h = idx >> 4, w = idx & 15;
    lds[h*17 + w] = in[planeBase + (size_t)h*WDIM + w];
  }
  __syncthreads();
  int u = tid >> 4, t = tid & 15;
  cplx vv[16];
  #pragma unroll
  for (int a = 0; a < 16; ++a) vv[a] = lds[(16*a + t)*17 + u];
  fft256_16<INV>(vv, t, lds + u*280);
  #pragma unroll
  for (int d = 0; d < 16; ++d) v[d] = vv[d];
}

__global__ __launch_bounds__(256) void k_col_fwd(cplx* __restrict__ buf) {
  __shared__ cplx lds[4480];
  size_t planeBase = (size_t)blockIdx.y*HW + blockIdx.x*16;
  cplx v[16];
  col_core<false>(buf, lds, v, planeBase);
  int u = threadIdx.x >> 4, t = threadIdx.x & 15;
  #pragma unroll
  for (int d = 0; d < 16; ++d) lds[(t + 16*d)*17 + u] = v[d];
  __syncthreads();
  int tid = threadIdx.x;
  #pragma unroll
  for (int i = 0; i < 16; ++i) {
    int idx = tid + 256*i; int h = idx >> 4, w = idx & 15;
    buf[planeBase + (size_t)h*WDIM + w] = lds[h*17 + w];
  }
}

// packed inverse cols: plane bp=(b,p) -> x[b,2p]=Re, x[b,2p+1]=Im;
// zt = x+u2 written DIRECTLY in bf16 channel-last (kills the planar ZT round-trip)
__global__ __launch_bounds__(256) void k_col_inv_xzt_p(const cplx* __restrict__ in,
                                                       const float* __restrict__ u2,
                                                       float* __restrict__ xout,
                                                       unsigned short* __restrict__ ztcl) {
  __shared__ cplx lds[4480];
  int bp = blockIdx.y; int bb = bp >> 4, p = bp & 15;
  size_t planeBase = (size_t)bp*HW + blockIdx.x*16;
  cplx v[16];
  col_core<true>(in, lds, v, planeBase);
  int u = threadIdx.x >> 4, t = threadIdx.x & 15;
  #pragma unroll
  for (int d = 0; d < 16; ++d) lds[(t + 16*d)*17 + u] = {v[d].x*(1.f/256.f), v[d].y*(1.f/256.f)};
  __syncthreads();
  int tid = threadIdx.x;
  size_t out0 = ((size_t)(bb*32 + 2*p))*HW + blockIdx.x*16;
  size_t out1 = out0 + HW;
  #pragma unroll
  for (int i = 0; i < 16; ++i) {
    int idx = tid + 256*i; int h = idx >> 4, w = idx & 15;
    cplx val = lds[h*17 + w];
    size_t g0 = out0 + (size_t)h*WDIM + w;
    size_t g1 = out1 + (size_t)h*WDIM + w;
    float zt0 = val.x + u2[g0];
    float zt1 = val.y + u2[g1];
    xout[g0] = val.x;
    xout[g1] = val.y;
    // channels 2p, 2p+1 of pixel (h, bx*16+w) are adjacent shorts in CL layout
    int pix = (h << 8) + (blockIdx.x << 4) + w;
    unsigned int pk = ((unsigned int)f2bf(zt1) << 16) | (unsigned int)f2bf(zt0);
    *(unsigned int*)(ztcl + ((((size_t)(bb << 16)) + pix) << 5) + 2*p) = pk;
  }
}

// inverse cols -> |.| (holo) + per-block min/max partials (small path)
__global__ __launch_bounds__(256) void k_col_inv_abs(const cplx* __restrict__ in,
                                                     float* __restrict__ holo,
                                                     float* __restrict__ partials) {
  __shared__ cplx lds[4480];
  float* ldsf = (float*)lds;
  size_t planeBase = (size_t)blockIdx.y*HW + blockIdx.x*16;
  cplx v[16];
  col_core<true>(in, lds, v, planeBase);
  int u = threadIdx.x >> 4, t = threadIdx.x & 15;
  #pragma unroll
  for (int d = 0; d < 16; ++d) {
    float re = v[d].x*(1.f/256.f), im = v[d].y*(1.f/256.f);
    ldsf[(t + 16*d)*17 + u] = sqrtf(re*re + im*im);
  }
  __syncthreads();
  int tid = threadIdx.x;
  float mn = 1e30f, mx = -1e30f;
  #pragma unroll
  for (int i = 0; i < 16; ++i) {
    int idx = tid + 256*i; int h = idx >> 4, w = idx & 15;
    float val = ldsf[h*17 + w];
    holo[planeBase + (size_t)h*WDIM + w] = val;
    mn = fminf(mn, val); mx = fmaxf(mx, val);
  }
  __syncthreads();
  #pragma unroll
  for (int s = 1; s < 64; s <<= 1) { mn = fminf(mn, __shfl_xor(mn, s)); mx = fmaxf(mx, __shfl_xor(mx, s)); }
  if ((tid & 63) == 0) { ldsf[(tid>>6)*2] = mn; ldsf[(tid>>6)*2 + 1] = mx; }
  __syncthreads();
  if (tid == 0) {
    float a = fminf(fminf(ldsf[0], ldsf[2]), fminf(ldsf[4], ldsf[6]));
    float b = fmaxf(fmaxf(ldsf[1], ldsf[3]), fmaxf(ldsf[5], ldsf[7]));
    partials[(blockIdx.y*16 + blockIdx.x)*2]     = a;
    partials[(blockIdx.y*16 + blockIdx.x)*2 + 1] = b;
  }
}

__global__ __launch_bounds__(64) void k_mm_reduce(const float* __restrict__ partials,
                                                  float* __restrict__ minmax) {
  int t = threadIdx.x; int b = t >> 4, i = t & 15;
  float mn = partials[(b*16 + i)*2], mx = partials[(b*16 + i)*2 + 1];
  #pragma unroll
  for (int s = 1; s < 16; s <<= 1) { mn = fminf(mn, __shfl_xor(mn, s)); mx = fmaxf(mx, __shfl_xor(mx, s)); }
  if (i == 0) { minmax[b*2] = mn; minmax[b*2 + 1] = mx; }
}

// ---------------- fused combine + HF (Hermitian-paired) ----------------------
// Every spectrum entering the X-solve is the FFT of a real field, so
// Xh[k2]=conj(Xh[k]) and both Q entries + both HF entries of a conjugate pair
// are computable from ONE set of loads.  Grid covers the half-space
// kh in [0,128]; rows 0 and 128 restrict to kw<=128 (self-mirror rows).
__global__ __launch_bounds__(256) void k_combine_hf(const cplx* __restrict__ P,
                                                    cplx* __restrict__ Q,
                                                    const cplx* __restrict__ X1F,
                                                    const float* __restrict__ otr,
                                                    const float* __restrict__ oti,
                                                    const float* __restrict__ r1p,
                                                    const float* __restrict__ r2p,
                                                    cplx* __restrict__ HF) {
  int j = blockIdx.x*256 + threadIdx.x;       // [4*129*256)
  int b = j / 33024;
  int r = j - b*33024;
  int kh = r >> 8, kw = r & 255;
  if ((kh == 0 || kh == 128) && kw > 128) return;
  int k  = (kh << 8) | kw;
  int k2 = ((((256 - kh) & 255)) << 8) | ((256 - kw) & 255);
  float rho1 = r1p[0], rho2 = r2p[0];
  cplx A  = X1F[(b << 16) | k];
  cplx Am = X1F[(b << 16) | k2];
  float hfr = 0.f, hfi = 0.f, hfr2 = 0.f, hfi2 = 0.f;
  #pragma unroll 1
  for (int p = 0; p < 16; ++p) {
    int pb = (b*16 + p) << 16;
    cplx Pk = P[pb | k], Pm = P[pb | k2];
    float Zr[2], Zi[2];
    Zr[0] = 0.5f*(Pk.x + Pm.x); Zi[0] = 0.5f*(Pk.y - Pm.y);
    Zr[1] = 0.5f*(Pk.y + Pm.y); Zi[1] = 0.5f*(Pm.x - Pk.x);
    float Xr[2], Xi[2];
    #pragma unroll
    for (int dd = 0; dd < 2; ++dd) {
      int db = (b*32 + 2*p + dd) << 16;
      float or1 = otr[db | k],  oi1 = oti[db | k];
      float or2 = otr[db | k2], oi2 = oti[db | k2];
      float Gr = 0.5f*(A.x*or1 + A.y*oi1 + Am.x*or2 + Am.y*oi2);
      float Gi = 0.5f*(A.y*or1 - A.x*oi1 + Am.x*oi2 - Am.y*or2);
      float di = 0.5f*(1.f/(rho2 + rho1*(or1*or1 + oi1*oi1))
                     + 1.f/(rho2 + rho1*(or2*or2 + oi2*oi2)));
      float xr = (rho1*Gr + rho2*Zr[dd])*di;
      float xi = (rho1*Gi + rho2*Zi[dd])*di;
      Xr[dd] = xr; Xi[dd] = xi;
      // HF[k]  += X_d[k]*otf_d[k]
      hfr  += xr*or1 - xi*oi1;
      hfi  += xr*oi1 + xi*or1;
      // HF[k2] += conj(X_d[k])*otf_d[k2]
      hfr2 += xr*or2 + xi*oi2;
      hfi2 += xr*oi2 - xi*or2;
    }
    Q[pb | k]  = {Xr[0] - Xi[1], Xi[0] + Xr[1]};   // X0 + i*X1 at k
    Q[pb | k2] = {Xr[0] + Xi[1], Xr[1] - Xi[0]};   // conj(X0) + i*conj(X1) at k2
  }
  HF[(b << 16) | k]  = {hfr,  hfi};
  HF[(b << 16) | k2] = {hfr2, hfi2};
}

// ---------------- Phi update -------------------------------------------------
__global__ __launch_bounds__(256) void k_bisect(const float* __restrict__ holo,
                                                const float* __restrict__ minmax,
                                                const float* __restrict__ u1,
                                                const int* __restrict__ K1,
                                                const float* __restrict__ r1p,
                                                float* __restrict__ phi_out,
                                                float* __restrict__ u1_out) {
  int i = blockIdx.x*256 + threadIdx.x;
  int b = i >> 16;
  float mn = minmax[2*b], mx = minmax[2*b + 1];
  float fp = (holo[i] - mn) / (mx - mn);
  float pt = fp + u1[i];
  float K1f = (float)K1[i];
  float K0 = 1.f - K1f;
  float rho1 = r1p[0];
  bool ind0i = (K1f == 0.f);
  bool ind0 = ind0i;
  float pmin = 1e-5f, pmax = 100.f, pave = 0.5f*(pmin + pmax);
  #pragma unroll 1
  for (int it = 0; it < 30; ++it) {
    float e = expf(pave);
    float t = (K0 - K1f/(e - 1.f)) + rho1*(pave - pt);
    bool ind1 = !ind0;
    if (t > 0.f && ind1) pmin = pave;
    if (t < 0.f && ind1) pmax = pave;
    ind0 = ind0 || (t == 0.f && ind1);
    if (!ind0) pave = 0.5f*(pmin + pmax);
  }
  float pn = ind0i ? (pt - K0/rho1) : pave;
  phi_out[i] = pn;
  u1_out[i]  = u1[i] + pn - fp;
}

// =============================================================================
//                        Z-update: MFMA conv pipeline
// =============================================================================
__global__ __launch_bounds__(256) void k_wprep(const float* __restrict__ w1a,
                                               const float* __restrict__ w1b,
                                               const float* __restrict__ w2a,
                                               const float* __restrict__ w2b,
                                               unsigned short* __restrict__ Ap) {
  int idx = blockIdx.x*256 + threadIdx.x;
  if (idx >= 4*9216) return;
  int wsel = idx / 9216, r = idx - wsel*9216;
  const float* w = wsel==0 ? w1a : wsel==1 ? w1b : wsel==2 ? w2a : w2b;
  int tap = r / 1024, r2 = r - tap*1024, oc = r2 >> 5, ic = r2 & 31;
  Ap[idx] = f2bf(w[(oc*32 + ic)*9 + tap]);
}

#define CONV_R 4
__global__ __launch_bounds__(256, 4) void k_conv(const unsigned short* __restrict__ inCL,
                                                 const unsigned short* __restrict__ Aprep,
                                                 unsigned short* __restrict__ outCL,
                                                 float* __restrict__ part,
                                                 int mode,
                                                 const float* __restrict__ scsh,
                                                 const float* __restrict__ thrp) {
  __shared__ unsigned short tile[6*66*32];
  __shared__ float sred[4][16][2];
  int tid = threadIdx.x;
  int bx = blockIdx.x, by = blockIdx.y, bz = blockIdx.z;
  int w0 = bx*64, h0 = by*CONV_R;
  float thr = (mode == 2) ? thrp[0] : 0.f;

  for (int idx = tid; idx < 6*264; idx += 256) {
    int lrow = idx/264, rem = idx - lrow*264;
    int lcol = rem >> 2, m = rem & 3;
    int grow = h0 - 1 + lrow, gcol = w0 - 1 + lcol;
    uint4 val = {0,0,0,0};
    if (grow >= 0 && grow < 256 && gcol >= 0 && gcol < 256) {
      uint4 raw = *(const uint4*)(inCL + (((size_t)(bz<<16) + (grow<<8) + gcol)<<5) + m*8);
      if (mode == 0) val = raw;
      else {
        unsigned short h8[8]; *(uint4*)h8 = raw;
        #pragma unroll
        for (int j = 0; j < 8; ++j) {
          float v = bf2f(h8[j]);
          if (mode == 1) { int ic = m*8+j; v = v*scsh[ic] + scsh[32+ic]; v = v > 0.f ? v : 0.01f*v; }
          else { float s = fabsf(v) - thr; s = s > 0.f ? s : 0.f; v = copysignf(s, v); }
          h8[j] = f2bf(v);
        }
        val = *(uint4*)h8;
      }
    }
    *(uint4*)&tile[(size_t)idx*8] = val;
  }

  int lane = tid & 63, w = tid >> 6;
  int q = lane >> 4, ln = lane & 15;
  int ocH = w & 1, s0 = w >> 1;
  short8 afrag[9];
  #pragma unroll
  for (int t = 0; t < 9; ++t)
    afrag[t] = *(const short8*)(Aprep + ((t*32 + ocH*16 + ln)*32 + q*8));
  __syncthreads();

  float sacc[4] = {0,0,0,0}, s2acc[4] = {0,0,0,0};
  #pragma unroll
  for (int r = 0; r < CONV_R; ++r) {
    #pragma unroll
    for (int si = 0; si < 2; ++si) {
      int s = s0 + si*2;
      float4v acc = {0.f, 0.f, 0.f, 0.f};
      #pragma unroll
      for (int t = 0; t < 9; ++t) {
        int dy = t/3, dx = t - dy*3;
        int lrow = r + dy, lcol = s*16 + ln + dx;
        const short8 bfrag = *(const short8*)&tile[(lrow*66 + lcol)*32 + q*8];
        acc = __builtin_amdgcn_mfma_f32_16x16x32_bf16(afrag[t], bfrag, acc, 0, 0, 0);
      }
      int px = w0 + s*16 + ln, row = h0 + r;
      size_t obase = ((((size_t)(bz<<16) + (row<<8) + px))<<5) + ocH*16 + q*4;
      unsigned short o4[4];
      #pragma unroll
      for (int u = 0; u < 4; ++u) { o4[u] = f2bf(acc[u]); sacc[u] += acc[u]; s2acc[u] += acc[u]*acc[u]; }
      *(uint2*)(outCL + obase) = *(uint2*)o4;
    }
  }

  #pragma unroll
  for (int u = 0; u < 4; ++u) {
    float a = sacc[u], b2 = s2acc[u];
    #pragma unroll
    for (int mq = 1; mq < 16; mq <<= 1) { a += __shfl_xor(a, mq); b2 += __shfl_xor(b2, mq); }
    if (ln == 0) { sred[w][q*4+u][0] = a; sred[w][q*4+u][1] = b2; }
  }
  __syncthreads();
  if (tid < 64) {
    int ocH2 = tid >> 5, i16 = (tid >> 1) & 15, st = tid & 1;
    float tot = sred[ocH2][i16][st] + sred[ocH2+2][i16][st];
    int oc = ocH2*16 + i16;
    int blk = ((bz<<6) + by)*4 + bx;
    part[(oc*2+st)*1024 + blk] = tot;
  }
}

// parallel BN-stat finalize: one block per output channel
__global__ __launch_bounds__(256) void k_finstats2(const float* __restrict__ part,
                                                   const float* __restrict__ g,
                                                   const float* __restrict__ beta,
                                                   float* __restrict__ SS) {
  __shared__ float red[8];
  int oc = blockIdx.x, t = threadIdx.x;
  const float* ps = part + oc*2048;
  float s  = ps[t] + ps[t+256] + ps[t+512] + ps[t+768];
  float s2 = ps[1024+t] + ps[1280+t] + ps[1536+t] + ps[1792+t];
  #pragma unroll
  for (int m = 1; m < 64; m <<= 1) { s += __shfl_xor(s, m); s2 += __shfl_xor(s2, m); }
  if ((t & 63) == 0) { red[(t>>6)*2] = s; red[(t>>6)*2+1] = s2; }
  __syncthreads();
  if (t == 0) {
    float S  = red[0] + red[2] + red[4] + red[6];
    float S2 = red[1] + red[3] + red[5] + red[7];
    const float N = 262144.f;
    float mean = S / N;
    float var  = S2 / N - mean*mean;
    float sc = g[oc] * rsqrtf(var + 1e-5f);
    SS[oc] = sc; SS[32+oc] = beta[oc] - mean*sc;
  }
}

__global__ __launch_bounds__(256) void k_h1cl(const unsigned short* __restrict__ zt,
                                              const unsigned short* __restrict__ c2,
                                              const float* __restrict__ SS,
                                              unsigned short* __restrict__ h1) {
  int idx = blockIdx.x*256 + threadIdx.x;
  int cg = idx & 3;
  uint4 za = *(const uint4*)(zt + (size_t)idx*8);
  uint4 ca = *(const uint4*)(c2 + (size_t)idx*8);
  unsigned short zs[8], cs[8], os[8];
  *(uint4*)zs = za; *(uint4*)cs = ca;
  #pragma unroll
  for (int j = 0; j < 8; ++j) {
    int c = cg*8 + j;
    float v = bf2f(zs[j]) + bf2f(cs[j])*SS[c] + SS[32+c];
    v = v > 0.f ? v : 0.01f*v;
    os[j] = f2bf(v);
  }
  *(uint4*)(h1 + (size_t)idx*8) = *(uint4*)os;
}

// fused finals: z, u2_next, sym (planar fp32)
__global__ __launch_bounds__(256) void k_finalAB(const unsigned short* __restrict__ h1,
                                                 const unsigned short* __restrict__ c4,
                                                 const unsigned short* __restrict__ c6,
                                                 const unsigned short* __restrict__ ztcl,
                                                 const float* __restrict__ SS4,
                                                 const float* __restrict__ SS6,
                                                 const float* __restrict__ thrp,
                                                 const float* __restrict__ u2,
                                                 const float* __restrict__ x,
                                                 float* __restrict__ zout,
                                                 float* __restrict__ u2out,
                                                 float* __restrict__ symout) {
  __shared__ float zT[32*66];
  __shared__ float sT[32*66];
  int tid = threadIdx.x;
  size_t b = blockIdx.y;
  int px0 = blockIdx.x*64;
  float thr = thrp[0];
  int px = tid >> 2, cg = tid & 3;
  size_t cbase = ((((b<<16) + px0 + px))<<5) + cg*8;
  uint4 ha = *(const uint4*)(h1 + cbase);
  uint4 c4a = *(const uint4*)(c4 + cbase);
  uint4 c6a = *(const uint4*)(c6 + cbase);
  uint4 za = *(const uint4*)(ztcl + cbase);
  unsigned short hs[8], c4s[8], c6s[8], zs[8];
  *(uint4*)hs = ha; *(uint4*)c4s = c4a; *(uint4*)c6s = c6a; *(uint4*)zs = za;
  #pragma unroll
  for (int j = 0; j < 8; ++j) {
    int c = cg*8+j;
    float hv = bf2f(hs[j]);
    float s = fabsf(hv) - thr; s = s > 0.f ? s : 0.f;
    float th = copysignf(s, hv);
    float zv = th + bf2f(c4s[j])*SS4[c] + SS4[32+c];
    zT[c*66 + px] = zv > 0.f ? zv : 0.01f*zv;
    float xv = hv + bf2f(c6s[j])*SS6[c] + SS6[32+c];
    xv = xv > 0.f ? xv : 0.01f*xv;
    sT[c*66 + px] = xv - bf2f(zs[j]);
  }
  __syncthreads();
  #pragma unroll
  for (int i = 0; i < 2; ++i) {
    int ch = tid + i*256; int c = ch >> 4, p4 = (ch & 15)*4;
    size_t g = ((b*32 + c)<<16) + px0 + p4;
    float4 uv = *(const float4*)(u2 + g);
    float4 xv = *(const float4*)(x + g);
    float4 zv = { zT[c*66+p4], zT[c*66+p4+1], zT[c*66+p4+2], zT[c*66+p4+3] };
    float4 un = { uv.x+zv.x-xv.x, uv.y+zv.y-xv.y, uv.z+zv.z-xv.z, uv.w+zv.w-xv.w };
    float4 sv = { sT[c*66+p4], sT[c*66+p4+1], sT[c*66+p4+2], sT[c*66+p4+3] };
    *(float4*)(zout + g) = zv;
    *(float4*)(u2out + g) = un;
    *(float4*)(symout + g) = sv;
  }
}

// ================================================================================
extern "C" void kernel_launch(void* const* d_in, const int* in_sizes, int n_in,
                              void* d_out, int out_size, void* d_ws, size_t ws_size,
                              hipStream_t stream) {
  const float* phi  = (const float*)d_in[1];
  const float* z    = (const float*)d_in[2];
  const float* u1   = (const float*)d_in[3];
  const float* u2   = (const float*)d_in[4];
  const float* otr  = (const float*)d_in[5];
  const float* oti  = (const float*)d_in[6];
  const int*   K1   = (const int*)d_in[7];
  const float* rho1 = (const float*)d_in[8];
  const float* rho2 = (const float*)d_in[9];
  const float* sthr = (const float*)d_in[10];
  const float* w1a = (const float*)d_in[11];
  const float* g1a = (const float*)d_in[12];
  const float* b1a = (const float*)d_in[13];
  const float* w1b = (const float*)d_in[14];
  const float* g1b = (const float*)d_in[15];
  const float* b1b = (const float*)d_in[16];
  const float* w2a = (const float*)d_in[17];
  const float* g2a = (const float*)d_in[18];
  const float* b2a = (const float*)d_in[19];
  const float* w2b = (const float*)d_in[20];
  const float* g2b = (const float*)d_in[21];
  const float* b2b = (const float*)d_in[22];

  float* out = (float*)d_out;
  float* x_out   = out;                 // [B,D,H,W]
  float* phi_out = out + 8388608;
  float* z_out   = out + 8650752;
  float* u1_out  = out + 17039360;
  float* u2_out  = out + 17301504;
  float* sym_out = out + 25690112;

  char* ws = (char*)d_ws;
  cplx*  P     = (cplx*)ws;                          // 33.5 MB packed fwd spectrum
  cplx*  Q     = (cplx*)(ws + 33554432);             // 33.5 MB packed Xh spectrum
  cplx*  X1R   = (cplx*)(ws + 67108864);             // 2 MB: X1F, then HF-rows
  cplx*  HFT   = (cplx*)(ws + 69206016);             // 2 MB: HF
  float* holo  = (float*)(ws + 71303168);            // 1 MB
  float* partmm= (float*)(ws + 72351744);
  float* mm    = (float*)(ws + 72355840);

  unsigned short* Ap    = (unsigned short*)(ws + 71303168);   // over dead holo
  float*          part  = (float*)(ws + 71434240);
  float*          SSb   = (float*)(ws + 71696384);
  unsigned short* ZTcl  = (unsigned short*)(ws + 33554432);   // over dead Q lo
  unsigned short* H1cl  = (unsigned short*)(ws + 50331648);   // over dead Q hi
  unsigned short* C4cl  = (unsigned short*)(ws + 0);          // over dead P lo
  unsigned short* C2cl  = (unsigned short*)(ws + 16777216);   // over dead P hi
  unsigned short* C6cl  = (unsigned short*)(ws + 16777216);   // over dead C2cl (after h1cl)
  unsigned short* C135  = (unsigned short*)z_out;             // scratch (dead pre-finalAB)
  cplx* W2 = (cplx*)z_out;                                    // packed inverse rows

  // ---- X update (Fourier domain, packed pairs) ----
  k_row_fwd_sub  <<<dim3(16, 4),  256, 0, stream>>>(phi, u1, X1R);
  k_col_fwd      <<<dim3(16, 4),  256, 0, stream>>>(X1R);
  k_row_fwd_sub_p<<<dim3(16, 64), 256, 0, stream>>>(z, u2, P);
  k_col_fwd      <<<dim3(16, 64), 256, 0, stream>>>(P);
  k_combine_hf   <<<516, 256, 0, stream>>>(P, Q, X1R, otr, oti, rho1, rho2, HFT);
  // forward_proj: iFT(HF) -> |.| -> min/max
  k_row_inv      <<<dim3(16, 4),  256, 0, stream>>>(HFT, X1R);
  k_col_inv_abs  <<<dim3(16, 4),  256, 0, stream>>>(X1R, holo, partmm);
  k_mm_reduce    <<<1, 64, 0, stream>>>(partmm, mm);
  // x = iFT(Q) (packed), zt = x + u2 written straight to bf16 CL
  k_row_inv      <<<dim3(16, 64), 256, 0, stream>>>(Q, W2);
  k_col_inv_xzt_p<<<dim3(16, 64), 256, 0, stream>>>(W2, u2, x_out, ZTcl);
  // ---- Phi update ----
  k_bisect<<<1024, 256, 0, stream>>>(holo, mm, u1, K1, rho1, phi_out, u1_out);

  // ---- Z update ----
  k_wprep<<<144, 256, 0, stream>>>(w1a, w1b, w2a, w2b, Ap);

  dim3 cg(4, 64, 4);
  k_conv<<<cg, 256, 0, stream>>>(ZTcl, Ap + 0,      C135, part, 0, SSb,       sthr);
  k_finstats2<<<32, 256, 0, stream>>>(part, g1a, b1a, SSb + 0);
  k_conv<<<cg, 256, 0, stream>>>(C135, Ap + 9216,   C2cl, part, 1, SSb + 0,   sthr);
  k_finstats2<<<32, 256, 0, stream>>>(part, g1b, b1b, SSb + 64);
  k_h1cl<<<4096, 256, 0, stream>>>(ZTcl, C2cl, SSb + 64, H1cl);

  k_conv<<<cg, 256, 0, stream>>>(H1cl, Ap + 18432,  C135, part, 2, SSb,       sthr);
  k_finstats2<<<32, 256, 0, stream>>>(part, g2a, b2a, SSb + 128);
  k_conv<<<cg, 256, 0, stream>>>(C135, Ap + 27648,  C4cl, part, 1, SSb + 128, sthr);
  k_finstats2<<<32, 256, 0, stream>>>(part, g2b, b2b, SSb + 192);

  k_conv<<<cg, 256, 0, stream>>>(H1cl, Ap + 18432,  C135, part, 0, SSb,       sthr);
  k_finstats2<<<32, 256, 0, stream>>>(part, g2a, b2a, SSb + 256);
  k_conv<<<cg, 256, 0, stream>>>(C135, Ap + 27648,  C6cl, part, 1, SSb + 256, sthr);
  k_finstats2<<<32, 256, 0, stream>>>(part, g2b, b2b, SSb + 320);

  k_finalAB<<<dim3(1024, 4), 256, 0, stream>>>(H1cl, C4cl, C6cl, ZTcl,
                                               SSb + 192, SSb + 320, sthr, u2, x_out,
                                               z_out, u2_out, sym_out);
}

// Round 2
// 501.147 us; speedup vs baseline: 1.1981x; 1.1099x over previous
//
#include <hip/hip_runtime.h>
#include <math.h>

#define WDIM 256
#define HW   65536

struct cplx { float x, y; };
__device__ __forceinline__ cplx cmul(cplx a, cplx b){ return {a.x*b.x - a.y*b.y, a.x*b.y + a.y*b.x}; }
__device__ __forceinline__ cplx cadd(cplx a, cplx b){ return {a.x+b.x, a.y+b.y}; }
__device__ __forceinline__ cplx csub(cplx a, cplx b){ return {a.x-b.x, a.y-b.y}; }
__device__ __forceinline__ void swapc(cplx& a, cplx& b){ cplx t=a; a=b; b=t; }

typedef __attribute__((ext_vector_type(8))) short short8;
typedef __attribute__((ext_vector_type(4))) float float4v;

__device__ __forceinline__ unsigned short f2bf(float f){
  unsigned int u = __float_as_uint(f);
  unsigned int r = (u + 0x7FFFu + ((u >> 16) & 1u)) >> 16;
  return (unsigned short)r;
}
__device__ __forceinline__ float bf2f(unsigned short h){
  return __uint_as_float(((unsigned int)h) << 16);
}

// ---------------- 16-point FFT in registers (radix-2 DIT, bit-reversed input) ----
template<bool INV>
__device__ __forceinline__ void fft16(cplx v[16]) {
  const float C16[8] = {1.f, 0.9238795325112867f, 0.7071067811865476f, 0.3826834323650898f,
                        0.f, -0.3826834323650898f, -0.7071067811865476f, -0.9238795325112867f};
  const float S16[8] = {0.f, 0.3826834323650898f, 0.7071067811865476f, 0.9238795325112867f,
                        1.f, 0.9238795325112867f, 0.7071067811865476f, 0.3826834323650898f};
  swapc(v[1], v[8]); swapc(v[2], v[4]); swapc(v[3], v[12]);
  swapc(v[5], v[10]); swapc(v[7], v[14]); swapc(v[11], v[13]);
  #pragma unroll
  for (int s = 1; s <= 4; ++s) {
    const int m = 1 << s, half = m >> 1, step = 16 >> s;
    #pragma unroll
    for (int k = 0; k < 16; k += m) {
      #pragma unroll
      for (int j = 0; j < half; ++j) {
        cplx w = {C16[j*step], INV ? S16[j*step] : -S16[j*step]};
        cplx t = cmul(w, v[k+j+half]);
        v[k+j+half] = csub(v[k+j], t);
        v[k+j]      = cadd(v[k+j], t);
      }
    }
  }
}

template<bool INV>
__device__ void fft256_16(cplx v[16], int t, cplx* Yu) {
  fft16<INV>(v);
  float ang = (INV ? 6.283185307179586f : -6.283185307179586f) * (float)t * (1.0f/256.0f);
  float sn, cs; sincosf(ang, &sn, &cs);
  cplx wstep = {cs, sn}, w = {1.f, 0.f};
  #pragma unroll
  for (int c = 0; c < 16; ++c) { v[c] = cmul(v[c], w); w = cmul(w, wstep); }
  __syncthreads();
  #pragma unroll
  for (int c = 0; c < 16; ++c) Yu[t*17 + c] = v[c];
  __syncthreads();
  cplx z[16];
  #pragma unroll
  for (int b = 0; b < 16; ++b) z[b] = Yu[b*17 + t];
  fft16<INV>(z);
  #pragma unroll
  for (int d = 0; d < 16; ++d) v[d] = z[d];
  __syncthreads();
}

// ---------------- forward row FFT: packed z-u2 (planes<64) + packed phi-u1 (64,65)
__global__ __launch_bounds__(256) void k_row_fwd_all(const float* __restrict__ a,
                                                     const float* __restrict__ b,
                                                     const float* __restrict__ sa,
                                                     const float* __restrict__ sb,
                                                     cplx* __restrict__ P,
                                                     cplx* __restrict__ XS) {
  __shared__ cplx Y[16*280];
  int unit = threadIdx.x >> 4, t = threadIdx.x & 15;
  int bp = blockIdx.y;
  size_t rowoff = (size_t)(blockIdx.x*16 + unit)*WDIM;
  const float *pa, *pb;
  size_t base0, baseo_rel;
  cplx* outb;
  if (bp < 64) {
    int bb = bp >> 4, p = bp & 15;
    pa = a; pb = b;
    base0 = ((size_t)(bb*32 + 2*p))*HW + rowoff;
    outb = P; baseo_rel = (size_t)bp*HW + rowoff;
  } else {
    int pp = bp - 64;
    pa = sa; pb = sb;
    base0 = ((size_t)(2*pp))*HW + rowoff;
    outb = XS; baseo_rel = (size_t)pp*HW + rowoff;
  }
  size_t base1 = base0 + HW;
  cplx v[16];
  #pragma unroll
  for (int i = 0; i < 16; ++i) {
    size_t o = i*16 + t;
    v[i] = {pa[base0+o] - pb[base0+o], pa[base1+o] - pb[base1+o]};
  }
  fft256_16<false>(v, t, Y + unit*280);
  #pragma unroll
  for (int d = 0; d < 16; ++d) outb[baseo_rel + t + 16*d] = v[d];
}

// ---------------- column FFT core -------------------------------------------
template<bool INV>
__device__ void col_core(const cplx* __restrict__ in, cplx* lds, cplx v[16], size_t planeBase) {
  int tid = threadIdx.x;
  #pragma unroll
  for (int i = 0; i < 16; ++i) {
    int idx = tid + 256*i; int h = idx >> 4, w = idx & 15;
    lds[h*17 + w] = in[planeBase + (size_t)h*WDIM + w];
  }
  __syncthreads();
  int u = tid >> 4, t = tid & 15;
  cplx vv[16];
  #pragma unroll
  for (int a = 0; a < 16; ++a) vv[a] = lds[(16*a + t)*17 + u];
  fft256_16<INV>(vv, t, lds + u*280);
  #pragma unroll
  for (int d = 0; d < 16; ++d) v[d] = vv[d];
}

// forward cols over P (planes<64) and XS (64,65)
__global__ __launch_bounds__(256) void k_col_fwd_all(cplx* __restrict__ P,
                                                     cplx* __restrict__ XS) {
  __shared__ cplx lds[4480];
  int y = blockIdx.y;
  cplx* buf = (y < 64) ? (P + (size_t)y*HW) : (XS + (size_t)(y-64)*HW);
  size_t planeBase = blockIdx.x*16;
  cplx v[16];
  col_core<false>(buf, lds, v, planeBase);
  int u = threadIdx.x >> 4, t = threadIdx.x & 15;
  #pragma unroll
  for (int d = 0; d < 16; ++d) lds[(t + 16*d)*17 + u] = v[d];
  __syncthreads();
  int tid = threadIdx.x;
  #pragma unroll
  for (int i = 0; i < 16; ++i) {
    int idx = tid + 256*i; int h = idx >> 4, w = idx & 15;
    buf[planeBase + (size_t)h*WDIM + w] = lds[h*17 + w];
  }
}

// inverse rows: Q (planes<64) -> W2 ; HFT (4 planes) -> XS
__global__ __launch_bounds__(256) void k_row_inv_all(const cplx* __restrict__ Q,
                                                     const cplx* __restrict__ HFT,
                                                     cplx* __restrict__ W2,
                                                     cplx* __restrict__ XS) {
  __shared__ cplx Y[16*280];
  int unit = threadIdx.x >> 4, t = threadIdx.x & 15;
  int y = blockIdx.y;
  const cplx* inb;  cplx* outb;
  if (y < 64) { inb = Q + (size_t)y*HW; outb = W2 + (size_t)y*HW; }
  else        { inb = HFT + (size_t)(y-64)*HW; outb = XS + (size_t)(y-64)*HW; }
  size_t base = (size_t)(blockIdx.x*16 + unit)*WDIM;
  cplx v[16];
  #pragma unroll
  for (int i = 0; i < 16; ++i) v[i] = inb[base + i*16 + t];
  fft256_16<true>(v, t, Y + unit*280);
  #pragma unroll
  for (int d = 0; d < 16; ++d) outb[base + t + 16*d] = {v[d].x*(1.f/256.f), v[d].y*(1.f/256.f)};
}

// inverse cols, merged: y<64 -> x/zt path (W2); y>=64 -> |.|+minmax path (XS)
__global__ __launch_bounds__(256) void k_col_inv_all(const cplx* __restrict__ W2,
                                                     const cplx* __restrict__ XS,
                                                     const float* __restrict__ u2,
                                                     float* __restrict__ xout,
                                                     unsigned short* __restrict__ ztcl,
                                                     float* __restrict__ holo,
                                                     float* __restrict__ partials) {
  __shared__ cplx lds[4480];
  int y = blockIdx.y;
  int tid = threadIdx.x;
  if (y < 64) {
    int bb = y >> 4, p = y & 15;
    cplx v[16];
    col_core<true>(W2 + (size_t)y*HW, lds, v, blockIdx.x*16);
    int u = tid >> 4, t = tid & 15;
    #pragma unroll
    for (int d = 0; d < 16; ++d) lds[(t + 16*d)*17 + u] = {v[d].x*(1.f/256.f), v[d].y*(1.f/256.f)};
    __syncthreads();
    size_t out0 = ((size_t)(bb*32 + 2*p))*HW + blockIdx.x*16;
    size_t out1 = out0 + HW;
    #pragma unroll
    for (int i = 0; i < 16; ++i) {
      int idx = tid + 256*i; int h = idx >> 4, w = idx & 15;
      cplx val = lds[h*17 + w];
      size_t g0 = out0 + (size_t)h*WDIM + w;
      size_t g1 = out1 + (size_t)h*WDIM + w;
      float zt0 = val.x + u2[g0];
      float zt1 = val.y + u2[g1];
      xout[g0] = val.x;
      xout[g1] = val.y;
      int pix = (h << 8) + (blockIdx.x << 4) + w;
      unsigned int pk = ((unsigned int)f2bf(zt1) << 16) | (unsigned int)f2bf(zt0);
      *(unsigned int*)(ztcl + ((((size_t)(bb << 16)) + pix) << 5) + 2*p) = pk;
    }
  } else {
    int py = y - 64;
    float* ldsf = (float*)lds;
    cplx v[16];
    col_core<true>(XS + (size_t)py*HW, lds, v, blockIdx.x*16);
    int u = tid >> 4, t = tid & 15;
    #pragma unroll
    for (int d = 0; d < 16; ++d) {
      float re = v[d].x*(1.f/256.f), im = v[d].y*(1.f/256.f);
      ldsf[(t + 16*d)*17 + u] = sqrtf(re*re + im*im);
    }
    __syncthreads();
    float mn = 1e30f, mx = -1e30f;
    size_t planeBase = (size_t)py*HW + blockIdx.x*16;
    #pragma unroll
    for (int i = 0; i < 16; ++i) {
      int idx = tid + 256*i; int h = idx >> 4, w = idx & 15;
      float val = ldsf[h*17 + w];
      holo[planeBase + (size_t)h*WDIM + w] = val;
      mn = fminf(mn, val); mx = fmaxf(mx, val);
    }
    __syncthreads();
    #pragma unroll
    for (int s = 1; s < 64; s <<= 1) { mn = fminf(mn, __shfl_xor(mn, s)); mx = fmaxf(mx, __shfl_xor(mx, s)); }
    if ((tid & 63) == 0) { ldsf[(tid>>6)*2] = mn; ldsf[(tid>>6)*2 + 1] = mx; }
    __syncthreads();
    if (tid == 0) {
      float a = fminf(fminf(ldsf[0], ldsf[2]), fminf(ldsf[4], ldsf[6]));
      float b = fmaxf(fmaxf(ldsf[1], ldsf[3]), fmaxf(ldsf[5], ldsf[7]));
      partials[(py*16 + blockIdx.x)*2]     = a;
      partials[(py*16 + blockIdx.x)*2 + 1] = b;
    }
  }
}

__global__ __launch_bounds__(64) void k_mm_reduce(const float* __restrict__ partials,
                                                  float* __restrict__ minmax) {
  int t = threadIdx.x; int b = t >> 4, i = t & 15;
  float mn = partials[(b*16 + i)*2], mx = partials[(b*16 + i)*2 + 1];
  #pragma unroll
  for (int s = 1; s < 16; s <<= 1) { mn = fminf(mn, __shfl_xor(mn, s)); mx = fmaxf(mx, __shfl_xor(mx, s)); }
  if (i == 0) { minmax[b*2] = mn; minmax[b*2 + 1] = mx; }
}

// ---------------- fused combine + HF (Hermitian-paired, packed small spectrum) ---
// XS plane c = FFT((phi-u1)[2c] + i*(phi-u1)[2c+1]).  A = F{phi-u1}[b][k] via the
// Hermitian split; Am = conj(A) since phi-u1 is real.
__global__ __launch_bounds__(256) void k_combine_hf(const cplx* __restrict__ P,
                                                    cplx* __restrict__ Q,
                                                    const cplx* __restrict__ XS,
                                                    const float* __restrict__ otr,
                                                    const float* __restrict__ oti,
                                                    const float* __restrict__ r1p,
                                                    const float* __restrict__ r2p,
                                                    cplx* __restrict__ HF) {
  int j = blockIdx.x*256 + threadIdx.x;       // [4*129*256)
  int b = j / 33024;
  int r = j - b*33024;
  int kh = r >> 8, kw = r & 255;
  if ((kh == 0 || kh == 128) && kw > 128) return;
  int k  = (kh << 8) | kw;
  int k2 = ((((256 - kh) & 255)) << 8) | ((256 - kw) & 255);
  float rho1 = r1p[0], rho2 = r2p[0];
  int c = b >> 1, par = b & 1;
  cplx Sk = XS[(c << 16) | k], Sm = XS[(c << 16) | k2];
  cplx A;
  if (par == 0) A = {0.5f*(Sk.x + Sm.x), 0.5f*(Sk.y - Sm.y)};
  else          A = {0.5f*(Sk.y + Sm.y), 0.5f*(Sm.x - Sk.x)};
  cplx Am = {A.x, -A.y};
  float hfr = 0.f, hfi = 0.f, hfr2 = 0.f, hfi2 = 0.f;
  #pragma unroll 1
  for (int p = 0; p < 16; ++p) {
    int pb = (b*16 + p) << 16;
    cplx Pk = P[pb | k], Pm = P[pb | k2];
    float Zr[2], Zi[2];
    Zr[0] = 0.5f*(Pk.x + Pm.x); Zi[0] = 0.5f*(Pk.y - Pm.y);
    Zr[1] = 0.5f*(Pk.y + Pm.y); Zi[1] = 0.5f*(Pm.x - Pk.x);
    float Xr[2], Xi[2];
    #pragma unroll
    for (int dd = 0; dd < 2; ++dd) {
      int db = (b*32 + 2*p + dd) << 16;
      float or1 = otr[db | k],  oi1 = oti[db | k];
      float or2 = otr[db | k2], oi2 = oti[db | k2];
      float Gr = 0.5f*(A.x*or1 + A.y*oi1 + Am.x*or2 + Am.y*oi2);
      float Gi = 0.5f*(A.y*or1 - A.x*oi1 + Am.x*oi2 - Am.y*or2);
      float di = 0.5f*(1.f/(rho2 + rho1*(or1*or1 + oi1*oi1))
                     + 1.f/(rho2 + rho1*(or2*or2 + oi2*oi2)));
      float xr = (rho1*Gr + rho2*Zr[dd])*di;
      float xi = (rho1*Gi + rho2*Zi[dd])*di;
      Xr[dd] = xr; Xi[dd] = xi;
      hfr  += xr*or1 - xi*oi1;
      hfi  += xr*oi1 + xi*or1;
      hfr2 += xr*or2 + xi*oi2;
      hfi2 += xr*oi2 - xi*or2;
    }
    Q[pb | k]  = {Xr[0] - Xi[1], Xi[0] + Xr[1]};
    Q[pb | k2] = {Xr[0] + Xi[1], Xr[1] - Xi[0]};
  }
  HF[(b << 16) | k]  = {hfr,  hfi};
  HF[(b << 16) | k2] = {hfr2, hfi2};
}

// ---------------- Phi update -------------------------------------------------
__global__ __launch_bounds__(256) void k_bisect(const float* __restrict__ holo,
                                                const float* __restrict__ minmax,
                                                const float* __restrict__ u1,
                                                const int* __restrict__ K1,
                                                const float* __restrict__ r1p,
                                                float* __restrict__ phi_out,
                                                float* __restrict__ u1_out) {
  int i = blockIdx.x*256 + threadIdx.x;
  int b = i >> 16;
  float mn = minmax[2*b], mx = minmax[2*b + 1];
  float fp = (holo[i] - mn) / (mx - mn);
  float pt = fp + u1[i];
  float K1f = (float)K1[i];
  float K0 = 1.f - K1f;
  float rho1 = r1p[0];
  bool ind0i = (K1f == 0.f);
  bool ind0 = ind0i;
  float pmin = 1e-5f, pmax = 100.f, pave = 0.5f*(pmin + pmax);
  #pragma unroll 1
  for (int it = 0; it < 30; ++it) {
    float e = expf(pave);
    float t = (K0 - K1f/(e - 1.f)) + rho1*(pave - pt);
    bool ind1 = !ind0;
    if (t > 0.f && ind1) pmin = pave;
    if (t < 0.f && ind1) pmax = pave;
    ind0 = ind0 || (t == 0.f && ind1);
    if (!ind0) pave = 0.5f*(pmin + pmax);
  }
  float pn = ind0i ? (pt - K0/rho1) : pave;
  phi_out[i] = pn;
  u1_out[i]  = u1[i] + pn - fp;
}

// =============================================================================
//                        Z-update: MFMA conv pipeline
// =============================================================================
__global__ __launch_bounds__(256) void k_wprep(const float* __restrict__ w1a,
                                               const float* __restrict__ w1b,
                                               const float* __restrict__ w2a,
                                               const float* __restrict__ w2b,
                                               unsigned short* __restrict__ Ap) {
  int idx = blockIdx.x*256 + threadIdx.x;
  if (idx >= 4*9216) return;
  int wsel = idx / 9216, r = idx - wsel*9216;
  const float* w = wsel==0 ? w1a : wsel==1 ? w1b : wsel==2 ? w2a : w2b;
  int tap = r / 1024, r2 = r - tap*1024, oc = r2 >> 5, ic = r2 & 31;
  Ap[idx] = f2bf(w[(oc*32 + ic)*9 + tap]);
}

#define CONV_R 4
__global__ __launch_bounds__(256, 4) void k_conv(const unsigned short* __restrict__ inCL,
                                                 const unsigned short* __restrict__ Aprep,
                                                 unsigned short* __restrict__ outCL,
                                                 float* __restrict__ part,
                                                 int mode,
                                                 const float* __restrict__ scsh,
                                                 const float* __restrict__ thrp) {
  __shared__ unsigned short tile[6*66*32];
  __shared__ float sred[4][16][2];
  int tid = threadIdx.x;
  int bx = blockIdx.x, by = blockIdx.y, bz = blockIdx.z;
  int w0 = bx*64, h0 = by*CONV_R;

  for (int idx = tid; idx < 6*264; idx += 256) {
    int lrow = idx/264, rem = idx - lrow*264;
    int lcol = rem >> 2, m = rem & 3;
    int grow = h0 - 1 + lrow, gcol = w0 - 1 + lcol;
    uint4 val = {0,0,0,0};
    if (grow >= 0 && grow < 256 && gcol >= 0 && gcol < 256) {
      uint4 raw = *(const uint4*)(inCL + (((size_t)(bz<<16) + (grow<<8) + gcol)<<5) + m*8);
      if (mode == 0) val = raw;
      else {
        unsigned short h8[8]; *(uint4*)h8 = raw;
        #pragma unroll
        for (int j = 0; j < 8; ++j) {
          float v = bf2f(h8[j]);
          int ic = m*8+j; v = v*scsh[ic] + scsh[32+ic]; v = v > 0.f ? v : 0.01f*v;
          h8[j] = f2bf(v);
        }
        val = *(uint4*)h8;
      }
    }
    *(uint4*)&tile[(size_t)idx*8] = val;
  }

  int lane = tid & 63, w = tid >> 6;
  int q = lane >> 4, ln = lane & 15;
  int ocH = w & 1, s0 = w >> 1;
  short8 afrag[9];
  #pragma unroll
  for (int t = 0; t < 9; ++t)
    afrag[t] = *(const short8*)(Aprep + ((t*32 + ocH*16 + ln)*32 + q*8));
  __syncthreads();

  float sacc[4] = {0,0,0,0}, s2acc[4] = {0,0,0,0};
  #pragma unroll
  for (int r = 0; r < CONV_R; ++r) {
    #pragma unroll
    for (int si = 0; si < 2; ++si) {
      int s = s0 + si*2;
      float4v acc = {0.f, 0.f, 0.f, 0.f};
      #pragma unroll
      for (int t = 0; t < 9; ++t) {
        int dy = t/3, dx = t - dy*3;
        int lrow = r + dy, lcol = s*16 + ln + dx;
        const short8 bfrag = *(const short8*)&tile[(lrow*66 + lcol)*32 + q*8];
        acc = __builtin_amdgcn_mfma_f32_16x16x32_bf16(afrag[t], bfrag, acc, 0, 0, 0);
      }
      int px = w0 + s*16 + ln, row = h0 + r;
      size_t obase = ((((size_t)(bz<<16) + (row<<8) + px))<<5) + ocH*16 + q*4;
      unsigned short o4[4];
      #pragma unroll
      for (int u = 0; u < 4; ++u) { o4[u] = f2bf(acc[u]); sacc[u] += acc[u]; s2acc[u] += acc[u]*acc[u]; }
      *(uint2*)(outCL + obase) = *(uint2*)o4;
    }
  }

  #pragma unroll
  for (int u = 0; u < 4; ++u) {
    float a = sacc[u], b2 = s2acc[u];
    #pragma unroll
    for (int mq = 1; mq < 16; mq <<= 1) { a += __shfl_xor(a, mq); b2 += __shfl_xor(b2, mq); }
    if (ln == 0) { sred[w][q*4+u][0] = a; sred[w][q*4+u][1] = b2; }
  }
  __syncthreads();
  if (tid < 64) {
    int ocH2 = tid >> 5, i16 = (tid >> 1) & 15, st = tid & 1;
    float tot = sred[ocH2][i16][st] + sred[ocH2+2][i16][st];
    int oc = ocH2*16 + i16;
    int blk = ((bz<<6) + by)*4 + bx;
    part[(oc*2+st)*1024 + blk] = tot;
  }
}

// dual-branch conv: input H1cl, branch T = soft-thresholded, branch R = raw.
// Same weights; two outputs + two partial-stat sets.  One read of H1cl.
__global__ __launch_bounds__(256, 3) void k_conv35(const unsigned short* __restrict__ inCL,
                                                   const unsigned short* __restrict__ Aprep,
                                                   unsigned short* __restrict__ outT,
                                                   unsigned short* __restrict__ outR,
                                                   float* __restrict__ partT,
                                                   float* __restrict__ partR,
                                                   const float* __restrict__ thrp) {
  __shared__ unsigned short tileR[6*66*32];
  __shared__ unsigned short tileT[6*66*32];
  __shared__ float sredT[4][16][2];
  __shared__ float sredR[4][16][2];
  int tid = threadIdx.x;
  int bx = blockIdx.x, by = blockIdx.y, bz = blockIdx.z;
  int w0 = bx*64, h0 = by*CONV_R;
  float thr = thrp[0];

  for (int idx = tid; idx < 6*264; idx += 256) {
    int lrow = idx/264, rem = idx - lrow*264;
    int lcol = rem >> 2, m = rem & 3;
    int grow = h0 - 1 + lrow, gcol = w0 - 1 + lcol;
    uint4 raw = {0,0,0,0}, thrv = {0,0,0,0};
    if (grow >= 0 && grow < 256 && gcol >= 0 && gcol < 256) {
      raw = *(const uint4*)(inCL + (((size_t)(bz<<16) + (grow<<8) + gcol)<<5) + m*8);
      unsigned short h8[8], t8[8]; *(uint4*)h8 = raw;
      #pragma unroll
      for (int j = 0; j < 8; ++j) {
        float v = bf2f(h8[j]);
        float s = fabsf(v) - thr; s = s > 0.f ? s : 0.f;
        t8[j] = f2bf(copysignf(s, v));
      }
      thrv = *(uint4*)t8;
    }
    *(uint4*)&tileR[(size_t)idx*8] = raw;
    *(uint4*)&tileT[(size_t)idx*8] = thrv;
  }

  int lane = tid & 63, w = tid >> 6;
  int q = lane >> 4, ln = lane & 15;
  int ocH = w & 1, s0 = w >> 1;
  short8 afrag[9];
  #pragma unroll
  for (int t = 0; t < 9; ++t)
    afrag[t] = *(const short8*)(Aprep + ((t*32 + ocH*16 + ln)*32 + q*8));
  __syncthreads();

  float saT[4] = {0,0,0,0}, s2T[4] = {0,0,0,0};
  float saR[4] = {0,0,0,0}, s2R[4] = {0,0,0,0};
  #pragma unroll
  for (int r = 0; r < CONV_R; ++r) {
    #pragma unroll
    for (int si = 0; si < 2; ++si) {
      int s = s0 + si*2;
      float4v accT = {0.f,0.f,0.f,0.f}, accR = {0.f,0.f,0.f,0.f};
      #pragma unroll
      for (int t = 0; t < 9; ++t) {
        int dy = t/3, dx = t - dy*3;
        int lrow = r + dy, lcol = s*16 + ln + dx;
        size_t off = ((size_t)(lrow*66 + lcol))*32 + q*8;
        const short8 bT = *(const short8*)&tileT[off];
        accT = __builtin_amdgcn_mfma_f32_16x16x32_bf16(afrag[t], bT, accT, 0, 0, 0);
        const short8 bR = *(const short8*)&tileR[off];
        accR = __builtin_amdgcn_mfma_f32_16x16x32_bf16(afrag[t], bR, accR, 0, 0, 0);
      }
      int px = w0 + s*16 + ln, row = h0 + r;
      size_t obase = ((((size_t)(bz<<16) + (row<<8) + px))<<5) + ocH*16 + q*4;
      unsigned short oT[4], oR[4];
      #pragma unroll
      for (int u = 0; u < 4; ++u) {
        oT[u] = f2bf(accT[u]); saT[u] += accT[u]; s2T[u] += accT[u]*accT[u];
        oR[u] = f2bf(accR[u]); saR[u] += accR[u]; s2R[u] += accR[u]*accR[u];
      }
      *(uint2*)(outT + obase) = *(uint2*)oT;
      *(uint2*)(outR + obase) = *(uint2*)oR;
    }
  }

  #pragma unroll
  for (int u = 0; u < 4; ++u) {
    float aT = saT[u], bT2 = s2T[u], aR = saR[u], bR2 = s2R[u];
    #pragma unroll
    for (int mq = 1; mq < 16; mq <<= 1) {
      aT += __shfl_xor(aT, mq); bT2 += __shfl_xor(bT2, mq);
      aR += __shfl_xor(aR, mq); bR2 += __shfl_xor(bR2, mq);
    }
    if (ln == 0) {
      sredT[w][q*4+u][0] = aT; sredT[w][q*4+u][1] = bT2;
      sredR[w][q*4+u][0] = aR; sredR[w][q*4+u][1] = bR2;
    }
  }
  __syncthreads();
  if (tid < 64) {
    int ocH2 = tid >> 5, i16 = (tid >> 1) & 15, st = tid & 1;
    int oc = ocH2*16 + i16;
    int blk = ((bz<<6) + by)*4 + bx;
    partT[(oc*2+st)*1024 + blk] = sredT[ocH2][i16][st] + sredT[ocH2+2][i16][st];
    partR[(oc*2+st)*1024 + blk] = sredR[ocH2][i16][st] + sredR[ocH2+2][i16][st];
  }
}

// merged conv4+conv6: z<4 -> branch A (inA, ssA, outA, partA); z>=4 -> branch B
__global__ __launch_bounds__(256, 4) void k_conv_pair(const unsigned short* __restrict__ inA,
                                                      const unsigned short* __restrict__ inB,
                                                      unsigned short* __restrict__ outA,
                                                      unsigned short* __restrict__ outB,
                                                      float* __restrict__ partA,
                                                      float* __restrict__ partB,
                                                      const float* __restrict__ ssA,
                                                      const float* __restrict__ ssB,
                                                      const unsigned short* __restrict__ Aprep) {
  __shared__ unsigned short tile[6*66*32];
  __shared__ float sred[4][16][2];
  int tid = threadIdx.x;
  int bx = blockIdx.x, by = blockIdx.y;
  int half = blockIdx.z >> 2, bz = blockIdx.z & 3;
  const unsigned short* inCL = half ? inB : inA;
  unsigned short* outCL = half ? outB : outA;
  const float* scsh = half ? ssB : ssA;
  float* part = half ? partB : partA;
  int w0 = bx*64, h0 = by*CONV_R;

  for (int idx = tid; idx < 6*264; idx += 256) {
    int lrow = idx/264, rem = idx - lrow*264;
    int lcol = rem >> 2, m = rem & 3;
    int grow = h0 - 1 + lrow, gcol = w0 - 1 + lcol;
    uint4 val = {0,0,0,0};
    if (grow >= 0 && grow < 256 && gcol >= 0 && gcol < 256) {
      uint4 raw = *(const uint4*)(inCL + (((size_t)(bz<<16) + (grow<<8) + gcol)<<5) + m*8);
      unsigned short h8[8]; *(uint4*)h8 = raw;
      #pragma unroll
      for (int j = 0; j < 8; ++j) {
        float v = bf2f(h8[j]);
        int ic = m*8+j; v = v*scsh[ic] + scsh[32+ic]; v = v > 0.f ? v : 0.01f*v;
        h8[j] = f2bf(v);
      }
      val = *(uint4*)h8;
    }
    *(uint4*)&tile[(size_t)idx*8] = val;
  }

  int lane = tid & 63, w = tid >> 6;
  int q = lane >> 4, ln = lane & 15;
  int ocH = w & 1, s0 = w >> 1;
  short8 afrag[9];
  #pragma unroll
  for (int t = 0; t < 9; ++t)
    afrag[t] = *(const short8*)(Aprep + ((t*32 + ocH*16 + ln)*32 + q*8));
  __syncthreads();

  float sacc[4] = {0,0,0,0}, s2acc[4] = {0,0,0,0};
  #pragma unroll
  for (int r = 0; r < CONV_R; ++r) {
    #pragma unroll
    for (int si = 0; si < 2; ++si) {
      int s = s0 + si*2;
      float4v acc = {0.f, 0.f, 0.f, 0.f};
      #pragma unroll
      for (int t = 0; t < 9; ++t) {
        int dy = t/3, dx = t - dy*3;
        int lrow = r + dy, lcol = s*16 + ln + dx;
        const short8 bfrag = *(const short8*)&tile[(lrow*66 + lcol)*32 + q*8];
        acc = __builtin_amdgcn_mfma_f32_16x16x32_bf16(afrag[t], bfrag, acc, 0, 0, 0);
      }
      int px = w0 + s*16 + ln, row = h0 + r;
      size_t obase = ((((size_t)(bz<<16) + (row<<8) + px))<<5) + ocH*16 + q*4;
      unsigned short o4[4];
      #pragma unroll
      for (int u = 0; u < 4; ++u) { o4[u] = f2bf(acc[u]); sacc[u] += acc[u]; s2acc[u] += acc[u]*acc[u]; }
      *(uint2*)(outCL + obase) = *(uint2*)o4;
    }
  }

  #pragma unroll
  for (int u = 0; u < 4; ++u) {
    float a = sacc[u], b2 = s2acc[u];
    #pragma unroll
    for (int mq = 1; mq < 16; mq <<= 1) { a += __shfl_xor(a, mq); b2 += __shfl_xor(b2, mq); }
    if (ln == 0) { sred[w][q*4+u][0] = a; sred[w][q*4+u][1] = b2; }
  }
  __syncthreads();
  if (tid < 64) {
    int ocH2 = tid >> 5, i16 = (tid >> 1) & 15, st = tid & 1;
    float tot = sred[ocH2][i16][st] + sred[ocH2+2][i16][st];
    int oc = ocH2*16 + i16;
    int blk = ((bz<<6) + by)*4 + bx;
    part[(oc*2+st)*1024 + blk] = tot;
  }
}

// parallel BN-stat finalize: one block per output channel
__global__ __launch_bounds__(256) void k_finstats2(const float* __restrict__ part,
                                                   const float* __restrict__ g,
                                                   const float* __restrict__ beta,
                                                   float* __restrict__ SS) {
  __shared__ float red[8];
  int oc = blockIdx.x, t = threadIdx.x;
  const float* ps = part + oc*2048;
  float s  = ps[t] + ps[t+256] + ps[t+512] + ps[t+768];
  float s2 = ps[1024+t] + ps[1280+t] + ps[1536+t] + ps[1792+t];
  #pragma unroll
  for (int m = 1; m < 64; m <<= 1) { s += __shfl_xor(s, m); s2 += __shfl_xor(s2, m); }
  if ((t & 63) == 0) { red[(t>>6)*2] = s; red[(t>>6)*2+1] = s2; }
  __syncthreads();
  if (t == 0) {
    float S  = red[0] + red[2] + red[4] + red[6];
    float S2 = red[1] + red[3] + red[5] + red[7];
    const float N = 262144.f;
    float mean = S / N;
    float var  = S2 / N - mean*mean;
    float sc = g[oc] * rsqrtf(var + 1e-5f);
    SS[oc] = sc; SS[32+oc] = beta[oc] - mean*sc;
  }
}

// dual variant: blocks 0-31 finalize partA -> SSa; 32-63 finalize partB -> SSc
__global__ __launch_bounds__(256) void k_finstats_dual(const float* __restrict__ pA,
                                                       const float* __restrict__ pB,
                                                       const float* __restrict__ g,
                                                       const float* __restrict__ beta,
                                                       float* __restrict__ SSa,
                                                       float* __restrict__ SSc) {
  __shared__ float red[8];
  int bxi = blockIdx.x;
  const float* part = bxi < 32 ? pA : pB;
  float* SS = bxi < 32 ? SSa : SSc;
  int oc = bxi & 31, t = threadIdx.x;
  const float* ps = part + oc*2048;
  float s  = ps[t] + ps[t+256] + ps[t+512] + ps[t+768];
  float s2 = ps[1024+t] + ps[1280+t] + ps[1536+t] + ps[1792+t];
  #pragma unroll
  for (int m = 1; m < 64; m <<= 1) { s += __shfl_xor(s, m); s2 += __shfl_xor(s2, m); }
  if ((t & 63) == 0) { red[(t>>6)*2] = s; red[(t>>6)*2+1] = s2; }
  __syncthreads();
  if (t == 0) {
    float S  = red[0] + red[2] + red[4] + red[6];
    float S2 = red[1] + red[3] + red[5] + red[7];
    const float N = 262144.f;
    float mean = S / N;
    float var  = S2 / N - mean*mean;
    float sc = g[oc] * rsqrtf(var + 1e-5f);
    SS[oc] = sc; SS[32+oc] = beta[oc] - mean*sc;
  }
}

__global__ __launch_bounds__(256) void k_h1cl(const unsigned short* __restrict__ zt,
                                              const unsigned short* __restrict__ c2,
                                              const float* __restrict__ SS,
                                              unsigned short* __restrict__ h1) {
  int idx = blockIdx.x*256 + threadIdx.x;
  int cg = idx & 3;
  uint4 za = *(const uint4*)(zt + (size_t)idx*8);
  uint4 ca = *(const uint4*)(c2 + (size_t)idx*8);
  unsigned short zs[8], cs[8], os[8];
  *(uint4*)zs = za; *(uint4*)cs = ca;
  #pragma unroll
  for (int j = 0; j < 8; ++j) {
    int c = cg*8 + j;
    float v = bf2f(zs[j]) + bf2f(cs[j])*SS[c] + SS[32+c];
    v = v > 0.f ? v : 0.01f*v;
    os[j] = f2bf(v);
  }
  *(uint4*)(h1 + (size_t)idx*8) = *(uint4*)os;
}

// fused finals: z, u2_next, sym (planar fp32)
__global__ __launch_bounds__(256) void k_finalAB(const unsigned short* __restrict__ h1,
                                                 const unsigned short* __restrict__ c4,
                                                 const unsigned short* __restrict__ c6,
                                                 const unsigned short* __restrict__ ztcl,
                                                 const float* __restrict__ SS4,
                                                 const float* __restrict__ SS6,
                                                 const float* __restrict__ thrp,
                                                 const float* __restrict__ u2,
                                                 const float* __restrict__ x,
                                                 float* __restrict__ zout,
                                                 float* __restrict__ u2out,
                                                 float* __restrict__ symout) {
  __shared__ float zT[32*66];
  __shared__ float sT[32*66];
  int tid = threadIdx.x;
  size_t b = blockIdx.y;
  int px0 = blockIdx.x*64;
  float thr = thrp[0];
  int px = tid >> 2, cg = tid & 3;
  size_t cbase = ((((b<<16) + px0 + px))<<5) + cg*8;
  uint4 ha = *(const uint4*)(h1 + cbase);
  uint4 c4a = *(const uint4*)(c4 + cbase);
  uint4 c6a = *(const uint4*)(c6 + cbase);
  uint4 za = *(const uint4*)(ztcl + cbase);
  unsigned short hs[8], c4s[8], c6s[8], zs[8];
  *(uint4*)hs = ha; *(uint4*)c4s = c4a; *(uint4*)c6s = c6a; *(uint4*)zs = za;
  #pragma unroll
  for (int j = 0; j < 8; ++j) {
    int c = cg*8+j;
    float hv = bf2f(hs[j]);
    float s = fabsf(hv) - thr; s = s > 0.f ? s : 0.f;
    float th = copysignf(s, hv);
    float zv = th + bf2f(c4s[j])*SS4[c] + SS4[32+c];
    zT[c*66 + px] = zv > 0.f ? zv : 0.01f*zv;
    float xv = hv + bf2f(c6s[j])*SS6[c] + SS6[32+c];
    xv = xv > 0.f ? xv : 0.01f*xv;
    sT[c*66 + px] = xv - bf2f(zs[j]);
  }
  __syncthreads();
  #pragma unroll
  for (int i = 0; i < 2; ++i) {
    int ch = tid + i*256; int c = ch >> 4, p4 = (ch & 15)*4;
    size_t g = ((b*32 + c)<<16) + px0 + p4;
    float4 uv = *(const float4*)(u2 + g);
    float4 xv = *(const float4*)(x + g);
    float4 zv = { zT[c*66+p4], zT[c*66+p4+1], zT[c*66+p4+2], zT[c*66+p4+3] };
    float4 un = { uv.x+zv.x-xv.x, uv.y+zv.y-xv.y, uv.z+zv.z-xv.z, uv.w+zv.w-xv.w };
    float4 sv = { sT[c*66+p4], sT[c*66+p4+1], sT[c*66+p4+2], sT[c*66+p4+3] };
    *(float4*)(zout + g) = zv;
    *(float4*)(u2out + g) = un;
    *(float4*)(symout + g) = sv;
  }
}

// ================================================================================
extern "C" void kernel_launch(void* const* d_in, const int* in_sizes, int n_in,
                              void* d_out, int out_size, void* d_ws, size_t ws_size,
                              hipStream_t stream) {
  const float* phi  = (const float*)d_in[1];
  const float* z    = (const float*)d_in[2];
  const float* u1   = (const float*)d_in[3];
  const float* u2   = (const float*)d_in[4];
  const float* otr  = (const float*)d_in[5];
  const float* oti  = (const float*)d_in[6];
  const int*   K1   = (const int*)d_in[7];
  const float* rho1 = (const float*)d_in[8];
  const float* rho2 = (const float*)d_in[9];
  const float* sthr = (const float*)d_in[10];
  const float* w1a = (const float*)d_in[11];
  const float* g1a = (const float*)d_in[12];
  const float* b1a = (const float*)d_in[13];
  const float* w1b = (const float*)d_in[14];
  const float* g1b = (const float*)d_in[15];
  const float* b1b = (const float*)d_in[16];
  const float* w2a = (const float*)d_in[17];
  const float* g2a = (const float*)d_in[18];
  const float* b2a = (const float*)d_in[19];
  const float* w2b = (const float*)d_in[20];
  const float* g2b = (const float*)d_in[21];
  const float* b2b = (const float*)d_in[22];

  float* out = (float*)d_out;
  float* x_out   = out;                 // [B,D,H,W]
  float* phi_out = out + 8388608;
  float* z_out   = out + 8650752;
  float* u1_out  = out + 17039360;
  float* u2_out  = out + 17301504;
  float* sym_out = out + 25690112;

  char* ws = (char*)d_ws;
  cplx*  P     = (cplx*)ws;                          // 33.5 MB packed fwd spectrum
  cplx*  Q     = (cplx*)(ws + 33554432);             // 33.5 MB packed Xh spectrum
  cplx*  XS    = (cplx*)(ws + 67108864);             // 2 MB: packed small spectrum / inv rows
  cplx*  HFT   = (cplx*)(ws + 69206016);             // 2 MB: HF
  float* holo  = (float*)(ws + 71303168);            // 1 MB
  float* partmm= (float*)(ws + 72351744);
  float* mm    = (float*)(ws + 72355840);

  unsigned short* Ap    = (unsigned short*)(ws + 71303168);   // over dead holo
  float*          part  = (float*)(ws + 71434240);            // 256 KB (inside dead holo)
  float*          partB = (float*)(ws + 69206016);            // over dead HFT
  float*          SSb   = (float*)(ws + 71696384);
  unsigned short* ZTcl  = (unsigned short*)(ws + 33554432);   // over dead Q lo
  unsigned short* H1cl  = (unsigned short*)(ws + 50331648);   // over dead Q hi
  unsigned short* C4cl  = (unsigned short*)(ws + 0);          // over dead P lo
  unsigned short* C2cl  = (unsigned short*)(ws + 16777216);   // over dead P hi
  unsigned short* C6cl  = (unsigned short*)(ws + 16777216);   // over dead C2cl (after h1cl)
  unsigned short* C135a = (unsigned short*)z_out;             // scratch (dead pre-finalAB)
  unsigned short* C135b = (unsigned short*)((char*)z_out + 16777216);
  cplx* W2 = (cplx*)z_out;                                    // packed inverse rows

  // ---- X update (Fourier domain, packed pairs; small path folded in) ----
  k_row_fwd_all <<<dim3(16, 66), 256, 0, stream>>>(z, u2, phi, u1, P, XS);
  k_col_fwd_all <<<dim3(16, 66), 256, 0, stream>>>(P, XS);
  k_combine_hf  <<<516, 256, 0, stream>>>(P, Q, XS, otr, oti, rho1, rho2, HFT);
  k_row_inv_all <<<dim3(16, 68), 256, 0, stream>>>(Q, HFT, W2, XS);
  k_col_inv_all <<<dim3(16, 68), 256, 0, stream>>>(W2, XS, u2, x_out, ZTcl, holo, partmm);
  k_mm_reduce   <<<1, 64, 0, stream>>>(partmm, mm);
  // ---- Phi update ----
  k_bisect<<<1024, 256, 0, stream>>>(holo, mm, u1, K1, rho1, phi_out, u1_out);

  // ---- Z update ----
  k_wprep<<<144, 256, 0, stream>>>(w1a, w1b, w2a, w2b, Ap);

  dim3 cg(4, 64, 4);
  k_conv<<<cg, 256, 0, stream>>>(ZTcl, Ap + 0,      C135a, part, 0, SSb,     sthr);
  k_finstats2<<<32, 256, 0, stream>>>(part, g1a, b1a, SSb + 0);
  k_conv<<<cg, 256, 0, stream>>>(C135a, Ap + 9216,  C2cl,  part, 1, SSb + 0, sthr);
  k_finstats2<<<32, 256, 0, stream>>>(part, g1b, b1b, SSb + 64);
  k_h1cl<<<4096, 256, 0, stream>>>(ZTcl, C2cl, SSb + 64, H1cl);

  // fused conv3 (thresholded h1) + conv5 (raw h1): one read of H1cl
  k_conv35<<<cg, 256, 0, stream>>>(H1cl, Ap + 18432, C135a, C135b, part, partB, sthr);
  k_finstats_dual<<<64, 256, 0, stream>>>(part, partB, g2a, b2a, SSb + 128, SSb + 256);
  // merged conv4 + conv6
  k_conv_pair<<<dim3(4, 64, 8), 256, 0, stream>>>(C135a, C135b, C4cl, C6cl,
                                                  part, partB, SSb + 128, SSb + 256,
                                                  Ap + 27648);
  k_finstats_dual<<<64, 256, 0, stream>>>(part, partB, g2b, b2b, SSb + 192, SSb + 320);

  k_finalAB<<<dim3(1024, 4), 256, 0, stream>>>(H1cl, C4cl, C6cl, ZTcl,
                                               SSb + 192, SSb + 320, sthr, u2, x_out,
                                               z_out, u2_out, sym_out);
}

// Round 4
// 482.697 us; speedup vs baseline: 1.2439x; 1.0382x over previous
//
#include <hip/hip_runtime.h>
#include <math.h>

#define WDIM 256
#define HW   65536

struct cplx { float x, y; };
__device__ __forceinline__ cplx cmul(cplx a, cplx b){ return {a.x*b.x - a.y*b.y, a.x*b.y + a.y*b.x}; }
__device__ __forceinline__ cplx cadd(cplx a, cplx b){ return {a.x+b.x, a.y+b.y}; }
__device__ __forceinline__ cplx csub(cplx a, cplx b){ return {a.x-b.x, a.y-b.y}; }
__device__ __forceinline__ void swapc(cplx& a, cplx& b){ cplx t=a; a=b; b=t; }

typedef __attribute__((ext_vector_type(8))) short short8;
typedef __attribute__((ext_vector_type(4))) float float4v;

__device__ __forceinline__ unsigned short f2bf(float f){
  unsigned int u = __float_as_uint(f);
  unsigned int r = (u + 0x7FFFu + ((u >> 16) & 1u)) >> 16;
  return (unsigned short)r;
}
__device__ __forceinline__ float bf2f(unsigned short h){
  return __uint_as_float(((unsigned int)h) << 16);
}

// ---------------- 16-point FFT in registers (radix-2 DIT, bit-reversed input) ----
template<bool INV>
__device__ __forceinline__ void fft16(cplx v[16]) {
  const float C16[8] = {1.f, 0.9238795325112867f, 0.7071067811865476f, 0.3826834323650898f,
                        0.f, -0.3826834323650898f, -0.7071067811865476f, -0.9238795325112867f};
  const float S16[8] = {0.f, 0.3826834323650898f, 0.7071067811865476f, 0.9238795325112867f,
                        1.f, 0.9238795325112867f, 0.7071067811865476f, 0.3826834323650898f};
  swapc(v[1], v[8]); swapc(v[2], v[4]); swapc(v[3], v[12]);
  swapc(v[5], v[10]); swapc(v[7], v[14]); swapc(v[11], v[13]);
  #pragma unroll
  for (int s = 1; s <= 4; ++s) {
    const int m = 1 << s, half = m >> 1, step = 16 >> s;
    #pragma unroll
    for (int k = 0; k < 16; k += m) {
      #pragma unroll
      for (int j = 0; j < half; ++j) {
        cplx w = {C16[j*step], INV ? S16[j*step] : -S16[j*step]};
        cplx t = cmul(w, v[k+j+half]);
        v[k+j+half] = csub(v[k+j], t);
        v[k+j]      = cadd(v[k+j], t);
      }
    }
  }
}

template<bool INV>
__device__ void fft256_16(cplx v[16], int t, cplx* Yu) {
  fft16<INV>(v);
  float ang = (INV ? 6.283185307179586f : -6.283185307179586f) * (float)t * (1.0f/256.0f);
  float sn, cs; sincosf(ang, &sn, &cs);
  cplx wstep = {cs, sn}, w = {1.f, 0.f};
  #pragma unroll
  for (int c = 0; c < 16; ++c) { v[c] = cmul(v[c], w); w = cmul(w, wstep); }
  __syncthreads();
  #pragma unroll
  for (int c = 0; c < 16; ++c) Yu[t*17 + c] = v[c];
  __syncthreads();
  cplx z[16];
  #pragma unroll
  for (int b = 0; b < 16; ++b) z[b] = Yu[b*17 + t];
  fft16<INV>(z);
  #pragma unroll
  for (int d = 0; d < 16; ++d) v[d] = z[d];
  __syncthreads();
}

// ---------------- forward row FFT: packed z-u2 (<64) + packed phi-u1 (64,65)
// blockIdx.y == 66: weight-prep slice (folded-in independent work)
__global__ __launch_bounds__(256) void k_row_fwd_all(const float* __restrict__ a,
                                                     const float* __restrict__ b,
                                                     const float* __restrict__ sa,
                                                     const float* __restrict__ sb,
                                                     cplx* __restrict__ P,
                                                     cplx* __restrict__ XS,
                                                     const float* __restrict__ w1a,
                                                     const float* __restrict__ w1b,
                                                     const float* __restrict__ w2a,
                                                     const float* __restrict__ w2b,
                                                     unsigned short* __restrict__ Ap) {
  __shared__ cplx Y[16*280];
  int bp = blockIdx.y;
  if (bp == 66) {
    int base = blockIdx.x * 2304;
    for (int r = threadIdx.x; r < 2304; r += 256) {
      int idx = base + r;
      int wsel = idx / 9216, rr = idx - wsel*9216;
      const float* w = wsel==0 ? w1a : wsel==1 ? w1b : wsel==2 ? w2a : w2b;
      int tap = rr / 1024, r2 = rr - tap*1024, oc = r2 >> 5, ic = r2 & 31;
      Ap[idx] = f2bf(w[(oc*32 + ic)*9 + tap]);
    }
    return;
  }
  int unit = threadIdx.x >> 4, t = threadIdx.x & 15;
  size_t rowoff = (size_t)(blockIdx.x*16 + unit)*WDIM;
  const float *pa, *pb;
  size_t base0, baseo_rel;
  cplx* outb;
  if (bp < 64) {
    int bb = bp >> 4, p = bp & 15;
    pa = a; pb = b;
    base0 = ((size_t)(bb*32 + 2*p))*HW + rowoff;
    outb = P; baseo_rel = (size_t)bp*HW + rowoff;
  } else {
    int pp = bp - 64;
    pa = sa; pb = sb;
    base0 = ((size_t)(2*pp))*HW + rowoff;
    outb = XS; baseo_rel = (size_t)pp*HW + rowoff;
  }
  size_t base1 = base0 + HW;
  cplx v[16];
  #pragma unroll
  for (int i = 0; i < 16; ++i) {
    size_t o = i*16 + t;
    v[i] = {pa[base0+o] - pb[base0+o], pa[base1+o] - pb[base1+o]};
  }
  fft256_16<false>(v, t, Y + unit*280);
  #pragma unroll
  for (int d = 0; d < 16; ++d) outb[baseo_rel + t + 16*d] = v[d];
}

// ---------------- column FFT core -------------------------------------------
template<bool INV>
__device__ void col_core(const cplx* __restrict__ in, cplx* lds, cplx v[16], size_t planeBase) {
  int tid = threadIdx.x;
  #pragma unroll
  for (int i = 0; i < 16; ++i) {
    int idx = tid + 256*i; int h = idx >> 4, w = idx & 15;
    lds[h*17 + w] = in[planeBase + (size_t)h*WDIM + w];
  }
  __syncthreads();
  int u = tid >> 4, t = tid & 15;
  cplx vv[16];
  #pragma unroll
  for (int a = 0; a < 16; ++a) vv[a] = lds[(16*a + t)*17 + u];
  fft256_16<INV>(vv, t, lds + u*280);
  #pragma unroll
  for (int d = 0; d < 16; ++d) v[d] = vv[d];
}

// forward cols over P (planes<64) and XS (64,65)
__global__ __launch_bounds__(256) void k_col_fwd_all(cplx* __restrict__ P,
                                                     cplx* __restrict__ XS) {
  __shared__ cplx lds[4480];
  int y = blockIdx.y;
  cplx* buf = (y < 64) ? (P + (size_t)y*HW) : (XS + (size_t)(y-64)*HW);
  size_t planeBase = blockIdx.x*16;
  cplx v[16];
  col_core<false>(buf, lds, v, planeBase);
  int u = threadIdx.x >> 4, t = threadIdx.x & 15;
  #pragma unroll
  for (int d = 0; d < 16; ++d) lds[(t + 16*d)*17 + u] = v[d];
  __syncthreads();
  int tid = threadIdx.x;
  #pragma unroll
  for (int i = 0; i < 16; ++i) {
    int idx = tid + 256*i; int h = idx >> 4, w = idx & 15;
    buf[planeBase + (size_t)h*WDIM + w] = lds[h*17 + w];
  }
}

// ---------------- fused combine + HF + row-IFFT (Q never hits HBM) -----------
// Block (kh, b): conjugate row pair (kh, 256-kh) of batch b.  Phase A computes
// Q rows for 8 planes into LDS; phase B row-IFFTs them straight to W2.  Two
// halves cover all 16 packed planes; a final pass does the 2 HF rows -> HFX.
__global__ __launch_bounds__(256) void k_combine_inv(const cplx* __restrict__ P,
                                                     const cplx* __restrict__ XS,
                                                     const float* __restrict__ otr,
                                                     const float* __restrict__ oti,
                                                     const float* __restrict__ r1p,
                                                     const float* __restrict__ r2p,
                                                     cplx* __restrict__ W2,
                                                     cplx* __restrict__ HFX) {
  __shared__ cplx R[16*273];
  int kw = threadIdx.x;
  int kh = blockIdx.x;                 // 0..128
  int b  = blockIdx.y;                 // 0..3
  int kh2 = (256 - kh) & 255;
  int kw2 = (256 - kw) & 255;
  int k  = (kh << 8) | kw;
  int k2 = (kh2 << 8) | kw2;
  float rho1 = r1p[0], rho2 = r2p[0];
  int c = b >> 1, par = b & 1;
  cplx Sk = XS[(c << 16) | k], Sm = XS[(c << 16) | k2];
  cplx A;
  if (par == 0) A = {0.5f*(Sk.x + Sm.x), 0.5f*(Sk.y - Sm.y)};
  else          A = {0.5f*(Sk.y + Sm.y), 0.5f*(Sm.x - Sk.x)};
  cplx Am = {A.x, -A.y};
  float hfr = 0.f, hfi = 0.f, hfr2 = 0.f, hfi2 = 0.f;
  int unit = threadIdx.x >> 4, t = threadIdx.x & 15;

  #pragma unroll 1
  for (int half = 0; half < 2; ++half) {
    #pragma unroll 1
    for (int pl = 0; pl < 8; ++pl) {
      int p = half*8 + pl;
      int pb = (b*16 + p) << 16;
      cplx Pk = P[pb | k], Pm = P[pb | k2];
      float Zr[2], Zi[2];
      Zr[0] = 0.5f*(Pk.x + Pm.x); Zi[0] = 0.5f*(Pk.y - Pm.y);
      Zr[1] = 0.5f*(Pk.y + Pm.y); Zi[1] = 0.5f*(Pm.x - Pk.x);
      float Xr[2], Xi[2];
      #pragma unroll
      for (int dd = 0; dd < 2; ++dd) {
        int db = (b*32 + 2*p + dd) << 16;
        float or1 = otr[db | k],  oi1 = oti[db | k];
        float or2 = otr[db | k2], oi2 = oti[db | k2];
        float Gr = 0.5f*(A.x*or1 + A.y*oi1 + Am.x*or2 + Am.y*oi2);
        float Gi = 0.5f*(A.y*or1 - A.x*oi1 + Am.x*oi2 - Am.y*or2);
        float di = 0.5f*(1.f/(rho2 + rho1*(or1*or1 + oi1*oi1))
                       + 1.f/(rho2 + rho1*(or2*or2 + oi2*oi2)));
        float xr = (rho1*Gr + rho2*Zr[dd])*di;
        float xi = (rho1*Gi + rho2*Zi[dd])*di;
        Xr[dd] = xr; Xi[dd] = xi;
        hfr  += xr*or1 - xi*oi1;
        hfi  += xr*oi1 + xi*or1;
        hfr2 += xr*or2 + xi*oi2;
        hfi2 += xr*oi2 - xi*or2;
      }
      R[(pl*2)*273 + kw]    = {Xr[0] - Xi[1], Xi[0] + Xr[1]};
      R[(pl*2+1)*273 + kw2] = {Xr[0] + Xi[1], Xr[1] - Xi[0]};
    }
    __syncthreads();
    // row-IFFT the 16 rows in LDS; unit u owns slot u (plane-pair layout)
    {
      cplx* slot = R + unit*273;
      cplx v[16];
      #pragma unroll
      for (int i = 0; i < 16; ++i) v[i] = slot[i*16 + t];
      fft256_16<true>(v, t, slot);
      int plane = b*16 + half*8 + (unit >> 1);
      int row = (unit & 1) ? kh2 : kh;
      size_t base = (size_t)plane*HW + (size_t)row*WDIM;
      #pragma unroll
      for (int d = 0; d < 16; ++d)
        W2[base + t + 16*d] = {v[d].x*(1.f/256.f), v[d].y*(1.f/256.f)};
    }
  }
  // HF rows
  R[0*273 + kw]  = {hfr,  hfi};
  R[1*273 + kw2] = {hfr2, hfi2};
  __syncthreads();
  {
    cplx* slot = R + (unit & 1)*273;   // redundant units recompute same row (benign)
    cplx v[16];
    #pragma unroll
    for (int i = 0; i < 16; ++i) v[i] = slot[i*16 + t];
    fft256_16<true>(v, t, slot);
    if (unit < 2) {
      int row = unit ? kh2 : kh;
      size_t base = (size_t)b*HW + (size_t)row*WDIM;
      #pragma unroll
      for (int d = 0; d < 16; ++d)
        HFX[base + t + 16*d] = {v[d].x*(1.f/256.f), v[d].y*(1.f/256.f)};
    }
  }
}

// inverse cols, merged: y<64 -> x/zt path (W2); y>=64 -> |.|+minmax path (HFX rows)
__global__ __launch_bounds__(256) void k_col_inv_all(const cplx* __restrict__ W2,
                                                     const cplx* __restrict__ XS,
                                                     const float* __restrict__ u2,
                                                     float* __restrict__ xout,
                                                     unsigned short* __restrict__ ztcl,
                                                     float* __restrict__ holo,
                                                     float* __restrict__ partials) {
  __shared__ cplx lds[4480];
  int y = blockIdx.y;
  int tid = threadIdx.x;
  if (y < 64) {
    int bb = y >> 4, p = y & 15;
    cplx v[16];
    col_core<true>(W2 + (size_t)y*HW, lds, v, blockIdx.x*16);
    int u = tid >> 4, t = tid & 15;
    #pragma unroll
    for (int d = 0; d < 16; ++d) lds[(t + 16*d)*17 + u] = {v[d].x*(1.f/256.f), v[d].y*(1.f/256.f)};
    __syncthreads();
    size_t out0 = ((size_t)(bb*32 + 2*p))*HW + blockIdx.x*16;
    size_t out1 = out0 + HW;
    #pragma unroll
    for (int i = 0; i < 16; ++i) {
      int idx = tid + 256*i; int h = idx >> 4, w = idx & 15;
      cplx val = lds[h*17 + w];
      size_t g0 = out0 + (size_t)h*WDIM + w;
      size_t g1 = out1 + (size_t)h*WDIM + w;
      float zt0 = val.x + u2[g0];
      float zt1 = val.y + u2[g1];
      xout[g0] = val.x;
      xout[g1] = val.y;
      int pix = (h << 8) + (blockIdx.x << 4) + w;
      unsigned int pk = ((unsigned int)f2bf(zt1) << 16) | (unsigned int)f2bf(zt0);
      *(unsigned int*)(ztcl + ((((size_t)(bb << 16)) + pix) << 5) + 2*p) = pk;
    }
  } else {
    int py = y - 64;
    float* ldsf = (float*)lds;
    cplx v[16];
    col_core<true>(XS + (size_t)py*HW, lds, v, blockIdx.x*16);
    int u = tid >> 4, t = tid & 15;
    #pragma unroll
    for (int d = 0; d < 16; ++d) {
      float re = v[d].x*(1.f/256.f), im = v[d].y*(1.f/256.f);
      ldsf[(t + 16*d)*17 + u] = sqrtf(re*re + im*im);
    }
    __syncthreads();
    float mn = 1e30f, mx = -1e30f;
    size_t planeBase = (size_t)py*HW + blockIdx.x*16;
    #pragma unroll
    for (int i = 0; i < 16; ++i) {
      int idx = tid + 256*i; int h = idx >> 4, w = idx & 15;
      float val = ldsf[h*17 + w];
      holo[planeBase + (size_t)h*WDIM + w] = val;
      mn = fminf(mn, val); mx = fmaxf(mx, val);
    }
    __syncthreads();
    #pragma unroll
    for (int s = 1; s < 64; s <<= 1) { mn = fminf(mn, __shfl_xor(mn, s)); mx = fmaxf(mx, __shfl_xor(mx, s)); }
    if ((tid & 63) == 0) { ldsf[(tid>>6)*2] = mn; ldsf[(tid>>6)*2 + 1] = mx; }
    __syncthreads();
    if (tid == 0) {
      float a = fminf(fminf(ldsf[0], ldsf[2]), fminf(ldsf[4], ldsf[6]));
      float b = fmaxf(fmaxf(ldsf[1], ldsf[3]), fmaxf(ldsf[5], ldsf[7]));
      partials[(py*16 + blockIdx.x)*2]     = a;
      partials[(py*16 + blockIdx.x)*2 + 1] = b;
    }
  }
}

// ---------------- Phi update (min/max finalize folded in) --------------------
__global__ __launch_bounds__(256) void k_bisect(const float* __restrict__ holo,
                                                const float* __restrict__ partials,
                                                const float* __restrict__ u1,
                                                const int* __restrict__ K1,
                                                const float* __restrict__ r1p,
                                                float* __restrict__ phi_out,
                                                float* __restrict__ u1_out) {
  __shared__ float red2[2];
  int i = blockIdx.x*256 + threadIdx.x;
  int b = i >> 16;                      // whole block shares one b
  if (threadIdx.x < 16) {
    float mn = partials[(b*16 + threadIdx.x)*2];
    float mx = partials[(b*16 + threadIdx.x)*2 + 1];
    #pragma unroll
    for (int s = 1; s < 16; s <<= 1) { mn = fminf(mn, __shfl_xor(mn, s)); mx = fmaxf(mx, __shfl_xor(mx, s)); }
    if (threadIdx.x == 0) { red2[0] = mn; red2[1] = mx; }
  }
  __syncthreads();
  float mn = red2[0], mx = red2[1];
  float fp = (holo[i] - mn) / (mx - mn);
  float pt = fp + u1[i];
  float K1f = (float)K1[i];
  float K0 = 1.f - K1f;
  float rho1 = r1p[0];
  bool ind0i = (K1f == 0.f);
  bool ind0 = ind0i;
  float pmin = 1e-5f, pmax = 100.f, pave = 0.5f*(pmin + pmax);
  #pragma unroll 1
  for (int it = 0; it < 30; ++it) {
    float e = expf(pave);
    float t = (K0 - K1f/(e - 1.f)) + rho1*(pave - pt);
    bool ind1 = !ind0;
    if (t > 0.f && ind1) pmin = pave;
    if (t < 0.f && ind1) pmax = pave;
    ind0 = ind0 || (t == 0.f && ind1);
    if (!ind0) pave = 0.5f*(pmin + pmax);
  }
  float pn = ind0i ? (pt - K0/rho1) : pave;
  phi_out[i] = pn;
  u1_out[i]  = u1[i] + pn - fp;
}

// =============================================================================
//                        Z-update: MFMA conv pipeline
// =============================================================================
#define CONV_R 4
__global__ __launch_bounds__(256, 4) void k_conv(const unsigned short* __restrict__ inCL,
                                                 const unsigned short* __restrict__ Aprep,
                                                 unsigned short* __restrict__ outCL,
                                                 float* __restrict__ part,
                                                 int mode,
                                                 const float* __restrict__ scsh,
                                                 const float* __restrict__ thrp) {
  __shared__ unsigned short tile[6*66*32];
  __shared__ float sred[4][16][2];
  int tid = threadIdx.x;
  int bx = blockIdx.x, by = blockIdx.y, bz = blockIdx.z;
  int w0 = bx*64, h0 = by*CONV_R;

  for (int idx = tid; idx < 6*264; idx += 256) {
    int lrow = idx/264, rem = idx - lrow*264;
    int lcol = rem >> 2, m = rem & 3;
    int grow = h0 - 1 + lrow, gcol = w0 - 1 + lcol;
    uint4 val = {0,0,0,0};
    if (grow >= 0 && grow < 256 && gcol >= 0 && gcol < 256) {
      uint4 raw = *(const uint4*)(inCL + (((size_t)(bz<<16) + (grow<<8) + gcol)<<5) + m*8);
      if (mode == 0) val = raw;
      else {
        unsigned short h8[8]; *(uint4*)h8 = raw;
        #pragma unroll
        for (int j = 0; j < 8; ++j) {
          float v = bf2f(h8[j]);
          int ic = m*8+j; v = v*scsh[ic] + scsh[32+ic]; v = v > 0.f ? v : 0.01f*v;
          h8[j] = f2bf(v);
        }
        val = *(uint4*)h8;
      }
    }
    *(uint4*)&tile[(size_t)idx*8] = val;
  }

  int lane = tid & 63, w = tid >> 6;
  int q = lane >> 4, ln = lane & 15;
  int ocH = w & 1, s0 = w >> 1;
  short8 afrag[9];
  #pragma unroll
  for (int t = 0; t < 9; ++t)
    afrag[t] = *(const short8*)(Aprep + ((t*32 + ocH*16 + ln)*32 + q*8));
  __syncthreads();

  float sacc[4] = {0,0,0,0}, s2acc[4] = {0,0,0,0};
  #pragma unroll
  for (int r = 0; r < CONV_R; ++r) {
    #pragma unroll
    for (int si = 0; si < 2; ++si) {
      int s = s0 + si*2;
      float4v acc = {0.f, 0.f, 0.f, 0.f};
      #pragma unroll
      for (int t = 0; t < 9; ++t) {
        int dy = t/3, dx = t - dy*3;
        int lrow = r + dy, lcol = s*16 + ln + dx;
        const short8 bfrag = *(const short8*)&tile[(lrow*66 + lcol)*32 + q*8];
        acc = __builtin_amdgcn_mfma_f32_16x16x32_bf16(afrag[t], bfrag, acc, 0, 0, 0);
      }
      int px = w0 + s*16 + ln, row = h0 + r;
      size_t obase = ((((size_t)(bz<<16) + (row<<8) + px))<<5) + ocH*16 + q*4;
      unsigned short o4[4];
      #pragma unroll
      for (int u = 0; u < 4; ++u) { o4[u] = f2bf(acc[u]); sacc[u] += acc[u]; s2acc[u] += acc[u]*acc[u]; }
      *(uint2*)(outCL + obase) = *(uint2*)o4;
    }
  }

  #pragma unroll
  for (int u = 0; u < 4; ++u) {
    float a = sacc[u], b2 = s2acc[u];
    #pragma unroll
    for (int mq = 1; mq < 16; mq <<= 1) { a += __shfl_xor(a, mq); b2 += __shfl_xor(b2, mq); }
    if (ln == 0) { sred[w][q*4+u][0] = a; sred[w][q*4+u][1] = b2; }
  }
  __syncthreads();
  if (tid < 64) {
    int ocH2 = tid >> 5, i16 = (tid >> 1) & 15, st = tid & 1;
    float tot = sred[ocH2][i16][st] + sred[ocH2+2][i16][st];
    int oc = ocH2*16 + i16;
    int blk = ((bz<<6) + by)*4 + bx;
    part[(oc*2+st)*1024 + blk] = tot;
  }
}

// dual-branch conv: input H1cl, branch T = soft-thresholded, branch R = raw.
__global__ __launch_bounds__(256, 3) void k_conv35(const unsigned short* __restrict__ inCL,
                                                   const unsigned short* __restrict__ Aprep,
                                                   unsigned short* __restrict__ outT,
                                                   unsigned short* __restrict__ outR,
                                                   float* __restrict__ partT,
                                                   float* __restrict__ partR,
                                                   const float* __restrict__ thrp) {
  __shared__ unsigned short tileR[6*66*32];
  __shared__ unsigned short tileT[6*66*32];
  __shared__ float sredT[4][16][2];
  __shared__ float sredR[4][16][2];
  int tid = threadIdx.x;
  int bx = blockIdx.x, by = blockIdx.y, bz = blockIdx.z;
  int w0 = bx*64, h0 = by*CONV_R;
  float thr = thrp[0];

  for (int idx = tid; idx < 6*264; idx += 256) {
    int lrow = idx/264, rem = idx - lrow*264;
    int lcol = rem >> 2, m = rem & 3;
    int grow = h0 - 1 + lrow, gcol = w0 - 1 + lcol;
    uint4 raw = {0,0,0,0}, thrv = {0,0,0,0};
    if (grow >= 0 && grow < 256 && gcol >= 0 && gcol < 256) {
      raw = *(const uint4*)(inCL + (((size_t)(bz<<16) + (grow<<8) + gcol)<<5) + m*8);
      unsigned short h8[8], t8[8]; *(uint4*)h8 = raw;
      #pragma unroll
      for (int j = 0; j < 8; ++j) {
        float v = bf2f(h8[j]);
        float s = fabsf(v) - thr; s = s > 0.f ? s : 0.f;
        t8[j] = f2bf(copysignf(s, v));
      }
      thrv = *(uint4*)t8;
    }
    *(uint4*)&tileR[(size_t)idx*8] = raw;
    *(uint4*)&tileT[(size_t)idx*8] = thrv;
  }

  int lane = tid & 63, w = tid >> 6;
  int q = lane >> 4, ln = lane & 15;
  int ocH = w & 1, s0 = w >> 1;
  short8 afrag[9];
  #pragma unroll
  for (int t = 0; t < 9; ++t)
    afrag[t] = *(const short8*)(Aprep + ((t*32 + ocH*16 + ln)*32 + q*8));
  __syncthreads();

  float saT[4] = {0,0,0,0}, s2T[4] = {0,0,0,0};
  float saR[4] = {0,0,0,0}, s2R[4] = {0,0,0,0};
  #pragma unroll
  for (int r = 0; r < CONV_R; ++r) {
    #pragma unroll
    for (int si = 0; si < 2; ++si) {
      int s = s0 + si*2;
      float4v accT = {0.f,0.f,0.f,0.f}, accR = {0.f,0.f,0.f,0.f};
      #pragma unroll
      for (int t = 0; t < 9; ++t) {
        int dy = t/3, dx = t - dy*3;
        int lrow = r + dy, lcol = s*16 + ln + dx;
        size_t off = ((size_t)(lrow*66 + lcol))*32 + q*8;
        const short8 bT = *(const short8*)&tileT[off];
        accT = __builtin_amdgcn_mfma_f32_16x16x32_bf16(afrag[t], bT, accT, 0, 0, 0);
        const short8 bR = *(const short8*)&tileR[off];
        accR = __builtin_amdgcn_mfma_f32_16x16x32_bf16(afrag[t], bR, accR, 0, 0, 0);
      }
      int px = w0 + s*16 + ln, row = h0 + r;
      size_t obase = ((((size_t)(bz<<16) + (row<<8) + px))<<5) + ocH*16 + q*4;
      unsigned short oT[4], oR[4];
      #pragma unroll
      for (int u = 0; u < 4; ++u) {
        oT[u] = f2bf(accT[u]); saT[u] += accT[u]; s2T[u] += accT[u]*accT[u];
        oR[u] = f2bf(accR[u]); saR[u] += accR[u]; s2R[u] += accR[u]*accR[u];
      }
      *(uint2*)(outT + obase) = *(uint2*)oT;
      *(uint2*)(outR + obase) = *(uint2*)oR;
    }
  }

  #pragma unroll
  for (int u = 0; u < 4; ++u) {
    float aT = saT[u], bT2 = s2T[u], aR = saR[u], bR2 = s2R[u];
    #pragma unroll
    for (int mq = 1; mq < 16; mq <<= 1) {
      aT += __shfl_xor(aT, mq); bT2 += __shfl_xor(bT2, mq);
      aR += __shfl_xor(aR, mq); bR2 += __shfl_xor(bR2, mq);
    }
    if (ln == 0) {
      sredT[w][q*4+u][0] = aT; sredT[w][q*4+u][1] = bT2;
      sredR[w][q*4+u][0] = aR; sredR[w][q*4+u][1] = bR2;
    }
  }
  __syncthreads();
  if (tid < 64) {
    int ocH2 = tid >> 5, i16 = (tid >> 1) & 15, st = tid & 1;
    int oc = ocH2*16 + i16;
    int blk = ((bz<<6) + by)*4 + bx;
    partT[(oc*2+st)*1024 + blk] = sredT[ocH2][i16][st] + sredT[ocH2+2][i16][st];
    partR[(oc*2+st)*1024 + blk] = sredR[ocH2][i16][st] + sredR[ocH2+2][i16][st];
  }
}

// merged conv4+conv6: z<4 -> branch A; z>=4 -> branch B
__global__ __launch_bounds__(256, 4) void k_conv_pair(const unsigned short* __restrict__ inA,
                                                      const unsigned short* __restrict__ inB,
                                                      unsigned short* __restrict__ outA,
                                                      unsigned short* __restrict__ outB,
                                                      float* __restrict__ partA,
                                                      float* __restrict__ partB,
                                                      const float* __restrict__ ssA,
                                                      const float* __restrict__ ssB,
                                                      const unsigned short* __restrict__ Aprep) {
  __shared__ unsigned short tile[6*66*32];
  __shared__ float sred[4][16][2];
  int tid = threadIdx.x;
  int bx = blockIdx.x, by = blockIdx.y;
  int half = blockIdx.z >> 2, bz = blockIdx.z & 3;
  const unsigned short* inCL = half ? inB : inA;
  unsigned short* outCL = half ? outB : outA;
  const float* scsh = half ? ssB : ssA;
  float* part = half ? partB : partA;
  int w0 = bx*64, h0 = by*CONV_R;

  for (int idx = tid; idx < 6*264; idx += 256) {
    int lrow = idx/264, rem = idx - lrow*264;
    int lcol = rem >> 2, m = rem & 3;
    int grow = h0 - 1 + lrow, gcol = w0 - 1 + lcol;
    uint4 val = {0,0,0,0};
    if (grow >= 0 && grow < 256 && gcol >= 0 && gcol < 256) {
      uint4 raw = *(const uint4*)(inCL + (((size_t)(bz<<16) + (grow<<8) + gcol)<<5) + m*8);
      unsigned short h8[8]; *(uint4*)h8 = raw;
      #pragma unroll
      for (int j = 0; j < 8; ++j) {
        float v = bf2f(h8[j]);
        int ic = m*8+j; v = v*scsh[ic] + scsh[32+ic]; v = v > 0.f ? v : 0.01f*v;
        h8[j] = f2bf(v);
      }
      val = *(uint4*)h8;
    }
    *(uint4*)&tile[(size_t)idx*8] = val;
  }

  int lane = tid & 63, w = tid >> 6;
  int q = lane >> 4, ln = lane & 15;
  int ocH = w & 1, s0 = w >> 1;
  short8 afrag[9];
  #pragma unroll
  for (int t = 0; t < 9; ++t)
    afrag[t] = *(const short8*)(Aprep + ((t*32 + ocH*16 + ln)*32 + q*8));
  __syncthreads();

  float sacc[4] = {0,0,0,0}, s2acc[4] = {0,0,0,0};
  #pragma unroll
  for (int r = 0; r < CONV_R; ++r) {
    #pragma unroll
    for (int si = 0; si < 2; ++si) {
      int s = s0 + si*2;
      float4v acc = {0.f, 0.f, 0.f, 0.f};
      #pragma unroll
      for (int t = 0; t < 9; ++t) {
        int dy = t/3, dx = t - dy*3;
        int lrow = r + dy, lcol = s*16 + ln + dx;
        const short8 bfrag = *(const short8*)&tile[(lrow*66 + lcol)*32 + q*8];
        acc = __builtin_amdgcn_mfma_f32_16x16x32_bf16(afrag[t], bfrag, acc, 0, 0, 0);
      }
      int px = w0 + s*16 + ln, row = h0 + r;
      size_t obase = ((((size_t)(bz<<16) + (row<<8) + px))<<5) + ocH*16 + q*4;
      unsigned short o4[4];
      #pragma unroll
      for (int u = 0; u < 4; ++u) { o4[u] = f2bf(acc[u]); sacc[u] += acc[u]; s2acc[u] += acc[u]*acc[u]; }
      *(uint2*)(outCL + obase) = *(uint2*)o4;
    }
  }

  #pragma unroll
  for (int u = 0; u < 4; ++u) {
    float a = sacc[u], b2 = s2acc[u];
    #pragma unroll
    for (int mq = 1; mq < 16; mq <<= 1) { a += __shfl_xor(a, mq); b2 += __shfl_xor(b2, mq); }
    if (ln == 0) { sred[w][q*4+u][0] = a; sred[w][q*4+u][1] = b2; }
  }
  __syncthreads();
  if (tid < 64) {
    int ocH2 = tid >> 5, i16 = (tid >> 1) & 15, st = tid & 1;
    float tot = sred[ocH2][i16][st] + sred[ocH2+2][i16][st];
    int oc = ocH2*16 + i16;
    int blk = ((bz<<6) + by)*4 + bx;
    part[(oc*2+st)*1024 + blk] = tot;
  }
}

// parallel BN-stat finalize: one block per output channel
__global__ __launch_bounds__(256) void k_finstats2(const float* __restrict__ part,
                                                   const float* __restrict__ g,
                                                   const float* __restrict__ beta,
                                                   float* __restrict__ SS) {
  __shared__ float red[8];
  int oc = blockIdx.x, t = threadIdx.x;
  const float* ps = part + oc*2048;
  float s  = ps[t] + ps[t+256] + ps[t+512] + ps[t+768];
  float s2 = ps[1024+t] + ps[1280+t] + ps[1536+t] + ps[1792+t];
  #pragma unroll
  for (int m = 1; m < 64; m <<= 1) { s += __shfl_xor(s, m); s2 += __shfl_xor(s2, m); }
  if ((t & 63) == 0) { red[(t>>6)*2] = s; red[(t>>6)*2+1] = s2; }
  __syncthreads();
  if (t == 0) {
    float S  = red[0] + red[2] + red[4] + red[6];
    float S2 = red[1] + red[3] + red[5] + red[7];
    const float N = 262144.f;
    float mean = S / N;
    float var  = S2 / N - mean*mean;
    float sc = g[oc] * rsqrtf(var + 1e-5f);
    SS[oc] = sc; SS[32+oc] = beta[oc] - mean*sc;
  }
}

// dual variant: blocks 0-31 finalize pA -> SSa; 32-63 finalize pB -> SSc
__global__ __launch_bounds__(256) void k_finstats_dual(const float* __restrict__ pA,
                                                       const float* __restrict__ pB,
                                                       const float* __restrict__ g,
                                                       const float* __restrict__ beta,
                                                       float* __restrict__ SSa,
                                                       float* __restrict__ SSc) {
  __shared__ float red[8];
  int bxi = blockIdx.x;
  const float* part = bxi < 32 ? pA : pB;
  float* SS = bxi < 32 ? SSa : SSc;
  int oc = bxi & 31, t = threadIdx.x;
  const float* ps = part + oc*2048;
  float s  = ps[t] + ps[t+256] + ps[t+512] + ps[t+768];
  float s2 = ps[1024+t] + ps[1280+t] + ps[1536+t] + ps[1792+t];
  #pragma unroll
  for (int m = 1; m < 64; m <<= 1) { s += __shfl_xor(s, m); s2 += __shfl_xor(s2, m); }
  if ((t & 63) == 0) { red[(t>>6)*2] = s; red[(t>>6)*2+1] = s2; }
  __syncthreads();
  if (t == 0) {
    float S  = red[0] + red[2] + red[4] + red[6];
    float S2 = red[1] + red[3] + red[5] + red[7];
    const float N = 262144.f;
    float mean = S / N;
    float var  = S2 / N - mean*mean;
    float sc = g[oc] * rsqrtf(var + 1e-5f);
    SS[oc] = sc; SS[32+oc] = beta[oc] - mean*sc;
  }
}

__global__ __launch_bounds__(256) void k_h1cl(const unsigned short* __restrict__ zt,
                                              const unsigned short* __restrict__ c2,
                                              const float* __restrict__ SS,
                                              unsigned short* __restrict__ h1) {
  int idx = blockIdx.x*256 + threadIdx.x;
  int cg = idx & 3;
  uint4 za = *(const uint4*)(zt + (size_t)idx*8);
  uint4 ca = *(const uint4*)(c2 + (size_t)idx*8);
  unsigned short zs[8], cs[8], os[8];
  *(uint4*)zs = za; *(uint4*)cs = ca;
  #pragma unroll
  for (int j = 0; j < 8; ++j) {
    int c = cg*8 + j;
    float v = bf2f(zs[j]) + bf2f(cs[j])*SS[c] + SS[32+c];
    v = v > 0.f ? v : 0.01f*v;
    os[j] = f2bf(v);
  }
  *(uint4*)(h1 + (size_t)idx*8) = *(uint4*)os;
}

// fused finals: z, u2_next, sym (planar fp32)
__global__ __launch_bounds__(256) void k_finalAB(const unsigned short* __restrict__ h1,
                                                 const unsigned short* __restrict__ c4,
                                                 const unsigned short* __restrict__ c6,
                                                 const unsigned short* __restrict__ ztcl,
                                                 const float* __restrict__ SS4,
                                                 const float* __restrict__ SS6,
                                                 const float* __restrict__ thrp,
                                                 const float* __restrict__ u2,
                                                 const float* __restrict__ x,
                                                 float* __restrict__ zout,
                                                 float* __restrict__ u2out,
                                                 float* __restrict__ symout) {
  __shared__ float zT[32*66];
  __shared__ float sT[32*66];
  int tid = threadIdx.x;
  size_t b = blockIdx.y;
  int px0 = blockIdx.x*64;
  float thr = thrp[0];
  int px = tid >> 2, cg = tid & 3;
  size_t cbase = ((((b<<16) + px0 + px))<<5) + cg*8;
  uint4 ha = *(const uint4*)(h1 + cbase);
  uint4 c4a = *(const uint4*)(c4 + cbase);
  uint4 c6a = *(const uint4*)(c6 + cbase);
  uint4 za = *(const uint4*)(ztcl + cbase);
  unsigned short hs[8], c4s[8], c6s[8], zs[8];
  *(uint4*)hs = ha; *(uint4*)c4s = c4a; *(uint4*)c6s = c6a; *(uint4*)zs = za;
  #pragma unroll
  for (int j = 0; j < 8; ++j) {
    int c = cg*8+j;
    float hv = bf2f(hs[j]);
    float s = fabsf(hv) - thr; s = s > 0.f ? s : 0.f;
    float th = copysignf(s, hv);
    float zv = th + bf2f(c4s[j])*SS4[c] + SS4[32+c];
    zT[c*66 + px] = zv > 0.f ? zv : 0.01f*zv;
    float xv = hv + bf2f(c6s[j])*SS6[c] + SS6[32+c];
    xv = xv > 0.f ? xv : 0.01f*xv;
    sT[c*66 + px] = xv - bf2f(zs[j]);
  }
  __syncthreads();
  #pragma unroll
  for (int i = 0; i < 2; ++i) {
    int ch = tid + i*256; int c = ch >> 4, p4 = (ch & 15)*4;
    size_t g = ((b*32 + c)<<16) + px0 + p4;
    float4 uv = *(const float4*)(u2 + g);
    float4 xv = *(const float4*)(x + g);
    float4 zv = { zT[c*66+p4], zT[c*66+p4+1], zT[c*66+p4+2], zT[c*66+p4+3] };
    float4 un = { uv.x+zv.x-xv.x, uv.y+zv.y-xv.y, uv.z+zv.z-xv.z, uv.w+zv.w-xv.w };
    float4 sv = { sT[c*66+p4], sT[c*66+p4+1], sT[c*66+p4+2], sT[c*66+p4+3] };
    *(float4*)(zout + g) = zv;
    *(float4*)(u2out + g) = un;
    *(float4*)(symout + g) = sv;
  }
}

// ================================================================================
extern "C" void kernel_launch(void* const* d_in, const int* in_sizes, int n_in,
                              void* d_out, int out_size, void* d_ws, size_t ws_size,
                              hipStream_t stream) {
  const float* phi  = (const float*)d_in[1];
  const float* z    = (const float*)d_in[2];
  const float* u1   = (const float*)d_in[3];
  const float* u2   = (const float*)d_in[4];
  const float* otr  = (const float*)d_in[5];
  const float* oti  = (const float*)d_in[6];
  const int*   K1   = (const int*)d_in[7];
  const float* rho1 = (const float*)d_in[8];
  const float* rho2 = (const float*)d_in[9];
  const float* sthr = (const float*)d_in[10];
  const float* w1a = (const float*)d_in[11];
  const float* g1a = (const float*)d_in[12];
  const float* b1a = (const float*)d_in[13];
  const float* w1b = (const float*)d_in[14];
  const float* g1b = (const float*)d_in[15];
  const float* b1b = (const float*)d_in[16];
  const float* w2a = (const float*)d_in[17];
  const float* g2a = (const float*)d_in[18];
  const float* b2a = (const float*)d_in[19];
  const float* w2b = (const float*)d_in[20];
  const float* g2b = (const float*)d_in[21];
  const float* b2b = (const float*)d_in[22];

  float* out = (float*)d_out;
  float* x_out   = out;                 // [B,D,H,W]
  float* phi_out = out + 8388608;
  float* z_out   = out + 8650752;
  float* u1_out  = out + 17039360;
  float* u2_out  = out + 17301504;
  float* sym_out = out + 25690112;

  char* ws = (char*)d_ws;
  cplx*  P     = (cplx*)ws;                          // 33.5 MB packed fwd spectrum
  cplx*  XS    = (cplx*)(ws + 67108864);             // 1 MB packed small spectrum (2 planes)
  cplx*  HFX   = (cplx*)(ws + 69206016);             // 2 MB row-inverted HF
  float* holo  = (float*)(ws + 71303168);            // 1 MB (71303168..72351744)
  float* partmm= (float*)(ws + 72351744);

  // Ap must SURVIVE from kernel 1 until the last conv; place it in the free
  // 1 MB hole between XS end (68157440) and HFX (69206016).  (Round-3 bug:
  // Ap aliased holo, which is written AFTER Ap is prepared -> garbage weights.)
  unsigned short* Ap    = (unsigned short*)(ws + 68157440);
  float*          part  = (float*)(ws + 71434240);            // inside dead holo
  float*          partB = (float*)(ws + 69206016);            // over dead HFX
  float*          SSb   = (float*)(ws + 71696384);            // inside dead holo
  unsigned short* ZTcl  = (unsigned short*)(ws + 33554432);   // free region lo
  unsigned short* H1cl  = (unsigned short*)(ws + 50331648);   // free region hi
  unsigned short* C4cl  = (unsigned short*)(ws + 0);          // over dead P lo
  unsigned short* C2cl  = (unsigned short*)(ws + 16777216);   // over dead P hi
  unsigned short* C6cl  = (unsigned short*)(ws + 16777216);   // over dead C2cl
  unsigned short* C135a = (unsigned short*)z_out;             // scratch (dead pre-finalAB)
  unsigned short* C135b = (unsigned short*)((char*)z_out + 16777216);
  cplx* W2 = (cplx*)z_out;                                    // row-inverted Q planes

  // ---- X update (Fourier domain; Q kept on-chip) ----
  k_row_fwd_all <<<dim3(16, 67), 256, 0, stream>>>(z, u2, phi, u1, P, XS,
                                                   w1a, w1b, w2a, w2b, Ap);
  k_col_fwd_all <<<dim3(16, 66), 256, 0, stream>>>(P, XS);
  k_combine_inv <<<dim3(129, 4), 256, 0, stream>>>(P, XS, otr, oti, rho1, rho2, W2, HFX);
  k_col_inv_all <<<dim3(16, 68), 256, 0, stream>>>(W2, HFX, u2, x_out, ZTcl, holo, partmm);
  // ---- Phi update (min/max finalize folded in) ----
  k_bisect<<<1024, 256, 0, stream>>>(holo, partmm, u1, K1, rho1, phi_out, u1_out);

  // ---- Z update ----
  dim3 cg(4, 64, 4);
  k_conv<<<cg, 256, 0, stream>>>(ZTcl, Ap + 0,      C135a, part, 0, SSb,     sthr);
  k_finstats2<<<32, 256, 0, stream>>>(part, g1a, b1a, SSb + 0);
  k_conv<<<cg, 256, 0, stream>>>(C135a, Ap + 9216,  C2cl,  part, 1, SSb + 0, sthr);
  k_finstats2<<<32, 256, 0, stream>>>(part, g1b, b1b, SSb + 64);
  k_h1cl<<<4096, 256, 0, stream>>>(ZTcl, C2cl, SSb + 64, H1cl);

  k_conv35<<<cg, 256, 0, stream>>>(H1cl, Ap + 18432, C135a, C135b, part, partB, sthr);
  k_finstats_dual<<<64, 256, 0, stream>>>(part, partB, g2a, b2a, SSb + 128, SSb + 256);
  k_conv_pair<<<dim3(4, 64, 8), 256, 0, stream>>>(C135a, C135b, C4cl, C6cl,
                                                  part, partB, SSb + 128, SSb + 256,
                                                  Ap + 27648);
  k_finstats_dual<<<64, 256, 0, stream>>>(part, partB, g2b, b2b, SSb + 192, SSb + 320);

  k_finalAB<<<dim3(1024, 4), 256, 0, stream>>>(H1cl, C4cl, C6cl, ZTcl,
                                               SSb + 192, SSb + 320, sthr, u2, x_out,
                                               z_out, u2_out, sym_out);
}

// Round 5
// 468.966 us; speedup vs baseline: 1.2804x; 1.0293x over previous
//
#include <hip/hip_runtime.h>
#include <math.h>

#define WDIM 256
#define HW   65536

struct cplx { float x, y; };
__device__ __forceinline__ cplx cmul(cplx a, cplx b){ return {a.x*b.x - a.y*b.y, a.x*b.y + a.y*b.x}; }
__device__ __forceinline__ cplx cadd(cplx a, cplx b){ return {a.x+b.x, a.y+b.y}; }
__device__ __forceinline__ cplx csub(cplx a, cplx b){ return {a.x-b.x, a.y-b.y}; }
__device__ __forceinline__ void swapc(cplx& a, cplx& b){ cplx t=a; a=b; b=t; }

typedef __attribute__((ext_vector_type(8))) short short8;
typedef __attribute__((ext_vector_type(4))) float float4v;

__device__ __forceinline__ unsigned short f2bf(float f){
  unsigned int u = __float_as_uint(f);
  unsigned int r = (u + 0x7FFFu + ((u >> 16) & 1u)) >> 16;
  return (unsigned short)r;
}
__device__ __forceinline__ float bf2f(unsigned short h){
  return __uint_as_float(((unsigned int)h) << 16);
}

// ---------------- 16-point FFT in registers (radix-2 DIT, bit-reversed input) ----
template<bool INV>
__device__ __forceinline__ void fft16(cplx v[16]) {
  const float C16[8] = {1.f, 0.9238795325112867f, 0.7071067811865476f, 0.3826834323650898f,
                        0.f, -0.3826834323650898f, -0.7071067811865476f, -0.9238795325112867f};
  const float S16[8] = {0.f, 0.3826834323650898f, 0.7071067811865476f, 0.9238795325112867f,
                        1.f, 0.9238795325112867f, 0.7071067811865476f, 0.3826834323650898f};
  swapc(v[1], v[8]); swapc(v[2], v[4]); swapc(v[3], v[12]);
  swapc(v[5], v[10]); swapc(v[7], v[14]); swapc(v[11], v[13]);
  #pragma unroll
  for (int s = 1; s <= 4; ++s) {
    const int m = 1 << s, half = m >> 1, step = 16 >> s;
    #pragma unroll
    for (int k = 0; k < 16; k += m) {
      #pragma unroll
      for (int j = 0; j < half; ++j) {
        cplx w = {C16[j*step], INV ? S16[j*step] : -S16[j*step]};
        cplx t = cmul(w, v[k+j+half]);
        v[k+j+half] = csub(v[k+j], t);
        v[k+j]      = cadd(v[k+j], t);
      }
    }
  }
}

template<bool INV>
__device__ void fft256_16(cplx v[16], int t, cplx* Yu) {
  fft16<INV>(v);
  float ang = (INV ? 6.283185307179586f : -6.283185307179586f) * (float)t * (1.0f/256.0f);
  float sn, cs; sincosf(ang, &sn, &cs);
  cplx wstep = {cs, sn}, w = {1.f, 0.f};
  #pragma unroll
  for (int c = 0; c < 16; ++c) { v[c] = cmul(v[c], w); w = cmul(w, wstep); }
  __syncthreads();
  #pragma unroll
  for (int c = 0; c < 16; ++c) Yu[t*17 + c] = v[c];
  __syncthreads();
  cplx z[16];
  #pragma unroll
  for (int b = 0; b < 16; ++b) z[b] = Yu[b*17 + t];
  fft16<INV>(z);
  #pragma unroll
  for (int d = 0; d < 16; ++d) v[d] = z[d];
  __syncthreads();
}

// ---------------- forward row FFT: packed z-u2 (<64) + packed phi-u1 (64,65)
// blockIdx.y == 66: weight-prep slice (folded-in independent work)
__global__ __launch_bounds__(256) void k_row_fwd_all(const float* __restrict__ a,
                                                     const float* __restrict__ b,
                                                     const float* __restrict__ sa,
                                                     const float* __restrict__ sb,
                                                     cplx* __restrict__ P,
                                                     cplx* __restrict__ XS,
                                                     const float* __restrict__ w1a,
                                                     const float* __restrict__ w1b,
                                                     const float* __restrict__ w2a,
                                                     const float* __restrict__ w2b,
                                                     unsigned short* __restrict__ Ap) {
  __shared__ cplx Y[16*280];
  int bp = blockIdx.y;
  if (bp == 66) {
    int base = blockIdx.x * 2304;
    for (int r = threadIdx.x; r < 2304; r += 256) {
      int idx = base + r;
      int wsel = idx / 9216, rr = idx - wsel*9216;
      const float* w = wsel==0 ? w1a : wsel==1 ? w1b : wsel==2 ? w2a : w2b;
      int tap = rr / 1024, r2 = rr - tap*1024, oc = r2 >> 5, ic = r2 & 31;
      Ap[idx] = f2bf(w[(oc*32 + ic)*9 + tap]);
    }
    return;
  }
  int unit = threadIdx.x >> 4, t = threadIdx.x & 15;
  size_t rowoff = (size_t)(blockIdx.x*16 + unit)*WDIM;
  const float *pa, *pb;
  size_t base0, baseo_rel;
  cplx* outb;
  if (bp < 64) {
    int bb = bp >> 4, p = bp & 15;
    pa = a; pb = b;
    base0 = ((size_t)(bb*32 + 2*p))*HW + rowoff;
    outb = P; baseo_rel = (size_t)bp*HW + rowoff;
  } else {
    int pp = bp - 64;
    pa = sa; pb = sb;
    base0 = ((size_t)(2*pp))*HW + rowoff;
    outb = XS; baseo_rel = (size_t)pp*HW + rowoff;
  }
  size_t base1 = base0 + HW;
  cplx v[16];
  #pragma unroll
  for (int i = 0; i < 16; ++i) {
    size_t o = i*16 + t;
    v[i] = {pa[base0+o] - pb[base0+o], pa[base1+o] - pb[base1+o]};
  }
  fft256_16<false>(v, t, Y + unit*280);
  #pragma unroll
  for (int d = 0; d < 16; ++d) outb[baseo_rel + t + 16*d] = v[d];
}

// ---------------- column FFT core -------------------------------------------
template<bool INV>
__device__ void col_core(const cplx* __restrict__ in, cplx* lds, cplx v[16], size_t planeBase) {
  int tid = threadIdx.x;
  #pragma unroll
  for (int i = 0; i < 16; ++i) {
    int idx = tid + 256*i; int h = idx >> 4, w = idx & 15;
    lds[h*17 + w] = in[planeBase + (size_t)h*WDIM + w];
  }
  __syncthreads();
  int u = tid >> 4, t = tid & 15;
  cplx vv[16];
  #pragma unroll
  for (int a = 0; a < 16; ++a) vv[a] = lds[(16*a + t)*17 + u];
  fft256_16<INV>(vv, t, lds + u*280);
  #pragma unroll
  for (int d = 0; d < 16; ++d) v[d] = vv[d];
}

// forward cols over P (planes<64) and XS (64,65)
__global__ __launch_bounds__(256) void k_col_fwd_all(cplx* __restrict__ P,
                                                     cplx* __restrict__ XS) {
  __shared__ cplx lds[4480];
  int y = blockIdx.y;
  cplx* buf = (y < 64) ? (P + (size_t)y*HW) : (XS + (size_t)(y-64)*HW);
  size_t planeBase = blockIdx.x*16;
  cplx v[16];
  col_core<false>(buf, lds, v, planeBase);
  int u = threadIdx.x >> 4, t = threadIdx.x & 15;
  #pragma unroll
  for (int d = 0; d < 16; ++d) lds[(t + 16*d)*17 + u] = v[d];
  __syncthreads();
  int tid = threadIdx.x;
  #pragma unroll
  for (int i = 0; i < 16; ++i) {
    int idx = tid + 256*i; int h = idx >> 4, w = idx & 15;
    buf[planeBase + (size_t)h*WDIM + w] = lds[h*17 + w];
  }
}

// ---------------- fused combine + HF + row-IFFT (Q never hits HBM) -----------
__global__ __launch_bounds__(256) void k_combine_inv(const cplx* __restrict__ P,
                                                     const cplx* __restrict__ XS,
                                                     const float* __restrict__ otr,
                                                     const float* __restrict__ oti,
                                                     const float* __restrict__ r1p,
                                                     const float* __restrict__ r2p,
                                                     cplx* __restrict__ W2,
                                                     cplx* __restrict__ HFX) {
  __shared__ cplx R[16*273];
  int kw = threadIdx.x;
  int kh = blockIdx.x;                 // 0..128
  int b  = blockIdx.y;                 // 0..3
  int kh2 = (256 - kh) & 255;
  int kw2 = (256 - kw) & 255;
  int k  = (kh << 8) | kw;
  int k2 = (kh2 << 8) | kw2;
  float rho1 = r1p[0], rho2 = r2p[0];
  int c = b >> 1, par = b & 1;
  cplx Sk = XS[(c << 16) | k], Sm = XS[(c << 16) | k2];
  cplx A;
  if (par == 0) A = {0.5f*(Sk.x + Sm.x), 0.5f*(Sk.y - Sm.y)};
  else          A = {0.5f*(Sk.y + Sm.y), 0.5f*(Sm.x - Sk.x)};
  cplx Am = {A.x, -A.y};
  float hfr = 0.f, hfi = 0.f, hfr2 = 0.f, hfi2 = 0.f;
  int unit = threadIdx.x >> 4, t = threadIdx.x & 15;

  #pragma unroll 1
  for (int half = 0; half < 2; ++half) {
    #pragma unroll 1
    for (int pl = 0; pl < 8; ++pl) {
      int p = half*8 + pl;
      int pb = (b*16 + p) << 16;
      cplx Pk = P[pb | k], Pm = P[pb | k2];
      float Zr[2], Zi[2];
      Zr[0] = 0.5f*(Pk.x + Pm.x); Zi[0] = 0.5f*(Pk.y - Pm.y);
      Zr[1] = 0.5f*(Pk.y + Pm.y); Zi[1] = 0.5f*(Pm.x - Pk.x);
      float Xr[2], Xi[2];
      #pragma unroll
      for (int dd = 0; dd < 2; ++dd) {
        int db = (b*32 + 2*p + dd) << 16;
        float or1 = otr[db | k],  oi1 = oti[db | k];
        float or2 = otr[db | k2], oi2 = oti[db | k2];
        float Gr = 0.5f*(A.x*or1 + A.y*oi1 + Am.x*or2 + Am.y*oi2);
        float Gi = 0.5f*(A.y*or1 - A.x*oi1 + Am.x*oi2 - Am.y*or2);
        float di = 0.5f*(1.f/(rho2 + rho1*(or1*or1 + oi1*oi1))
                       + 1.f/(rho2 + rho1*(or2*or2 + oi2*oi2)));
        float xr = (rho1*Gr + rho2*Zr[dd])*di;
        float xi = (rho1*Gi + rho2*Zi[dd])*di;
        Xr[dd] = xr; Xi[dd] = xi;
        hfr  += xr*or1 - xi*oi1;
        hfi  += xr*oi1 + xi*or1;
        hfr2 += xr*or2 + xi*oi2;
        hfi2 += xr*oi2 - xi*or2;
      }
      R[(pl*2)*273 + kw]    = {Xr[0] - Xi[1], Xi[0] + Xr[1]};
      R[(pl*2+1)*273 + kw2] = {Xr[0] + Xi[1], Xr[1] - Xi[0]};
    }
    __syncthreads();
    {
      cplx* slot = R + unit*273;
      cplx v[16];
      #pragma unroll
      for (int i = 0; i < 16; ++i) v[i] = slot[i*16 + t];
      fft256_16<true>(v, t, slot);
      int plane = b*16 + half*8 + (unit >> 1);
      int row = (unit & 1) ? kh2 : kh;
      size_t base = (size_t)plane*HW + (size_t)row*WDIM;
      #pragma unroll
      for (int d = 0; d < 16; ++d)
        W2[base + t + 16*d] = {v[d].x*(1.f/256.f), v[d].y*(1.f/256.f)};
    }
  }
  // HF rows
  R[0*273 + kw]  = {hfr,  hfi};
  R[1*273 + kw2] = {hfr2, hfi2};
  __syncthreads();
  {
    cplx* slot = R + (unit & 1)*273;   // redundant units recompute same row (benign)
    cplx v[16];
    #pragma unroll
    for (int i = 0; i < 16; ++i) v[i] = slot[i*16 + t];
    fft256_16<true>(v, t, slot);
    if (unit < 2) {
      int row = unit ? kh2 : kh;
      size_t base = (size_t)b*HW + (size_t)row*WDIM;
      #pragma unroll
      for (int d = 0; d < 16; ++d)
        HFX[base + t + 16*d] = {v[d].x*(1.f/256.f), v[d].y*(1.f/256.f)};
    }
  }
}

// inverse cols, merged: y<64 -> x/zt path (W2); y>=64 -> |.|+minmax path (HFX rows)
__global__ __launch_bounds__(256) void k_col_inv_all(const cplx* __restrict__ W2,
                                                     const cplx* __restrict__ XS,
                                                     const float* __restrict__ u2,
                                                     float* __restrict__ xout,
                                                     unsigned short* __restrict__ ztcl,
                                                     float* __restrict__ holo,
                                                     float* __restrict__ partials) {
  __shared__ cplx lds[4480];
  int y = blockIdx.y;
  int tid = threadIdx.x;
  if (y < 64) {
    int bb = y >> 4, p = y & 15;
    cplx v[16];
    col_core<true>(W2 + (size_t)y*HW, lds, v, blockIdx.x*16);
    int u = tid >> 4, t = tid & 15;
    #pragma unroll
    for (int d = 0; d < 16; ++d) lds[(t + 16*d)*17 + u] = {v[d].x*(1.f/256.f), v[d].y*(1.f/256.f)};
    __syncthreads();
    size_t out0 = ((size_t)(bb*32 + 2*p))*HW + blockIdx.x*16;
    size_t out1 = out0 + HW;
    #pragma unroll
    for (int i = 0; i < 16; ++i) {
      int idx = tid + 256*i; int h = idx >> 4, w = idx & 15;
      cplx val = lds[h*17 + w];
      size_t g0 = out0 + (size_t)h*WDIM + w;
      size_t g1 = out1 + (size_t)h*WDIM + w;
      float zt0 = val.x + u2[g0];
      float zt1 = val.y + u2[g1];
      xout[g0] = val.x;
      xout[g1] = val.y;
      int pix = (h << 8) + (blockIdx.x << 4) + w;
      unsigned int pk = ((unsigned int)f2bf(zt1) << 16) | (unsigned int)f2bf(zt0);
      *(unsigned int*)(ztcl + ((((size_t)(bb << 16)) + pix) << 5) + 2*p) = pk;
    }
  } else {
    int py = y - 64;
    float* ldsf = (float*)lds;
    cplx v[16];
    col_core<true>(XS + (size_t)py*HW, lds, v, blockIdx.x*16);
    int u = tid >> 4, t = tid & 15;
    #pragma unroll
    for (int d = 0; d < 16; ++d) {
      float re = v[d].x*(1.f/256.f), im = v[d].y*(1.f/256.f);
      ldsf[(t + 16*d)*17 + u] = sqrtf(re*re + im*im);
    }
    __syncthreads();
    float mn = 1e30f, mx = -1e30f;
    size_t planeBase = (size_t)py*HW + blockIdx.x*16;
    #pragma unroll
    for (int i = 0; i < 16; ++i) {
      int idx = tid + 256*i; int h = idx >> 4, w = idx & 15;
      float val = ldsf[h*17 + w];
      holo[planeBase + (size_t)h*WDIM + w] = val;
      mn = fminf(mn, val); mx = fmaxf(mx, val);
    }
    __syncthreads();
    #pragma unroll
    for (int s = 1; s < 64; s <<= 1) { mn = fminf(mn, __shfl_xor(mn, s)); mx = fmaxf(mx, __shfl_xor(mx, s)); }
    if ((tid & 63) == 0) { ldsf[(tid>>6)*2] = mn; ldsf[(tid>>6)*2 + 1] = mx; }
    __syncthreads();
    if (tid == 0) {
      float a = fminf(fminf(ldsf[0], ldsf[2]), fminf(ldsf[4], ldsf[6]));
      float b = fmaxf(fmaxf(ldsf[1], ldsf[3]), fmaxf(ldsf[5], ldsf[7]));
      partials[(py*16 + blockIdx.x)*2]     = a;
      partials[(py*16 + blockIdx.x)*2 + 1] = b;
    }
  }
}

// ---------------- Phi update (min/max finalize folded in) --------------------
__global__ __launch_bounds__(256) void k_bisect(const float* __restrict__ holo,
                                                const float* __restrict__ partials,
                                                const float* __restrict__ u1,
                                                const int* __restrict__ K1,
                                                const float* __restrict__ r1p,
                                                float* __restrict__ phi_out,
                                                float* __restrict__ u1_out) {
  __shared__ float red2[2];
  int i = blockIdx.x*256 + threadIdx.x;
  int b = i >> 16;                      // whole block shares one b
  if (threadIdx.x < 16) {
    float mn = partials[(b*16 + threadIdx.x)*2];
    float mx = partials[(b*16 + threadIdx.x)*2 + 1];
    #pragma unroll
    for (int s = 1; s < 16; s <<= 1) { mn = fminf(mn, __shfl_xor(mn, s)); mx = fmaxf(mx, __shfl_xor(mx, s)); }
    if (threadIdx.x == 0) { red2[0] = mn; red2[1] = mx; }
  }
  __syncthreads();
  float mn = red2[0], mx = red2[1];
  float fp = (holo[i] - mn) / (mx - mn);
  float pt = fp + u1[i];
  float K1f = (float)K1[i];
  float K0 = 1.f - K1f;
  float rho1 = r1p[0];
  bool ind0i = (K1f == 0.f);
  bool ind0 = ind0i;
  float pmin = 1e-5f, pmax = 100.f, pave = 0.5f*(pmin + pmax);
  #pragma unroll 1
  for (int it = 0; it < 30; ++it) {
    float e = expf(pave);
    float t = (K0 - K1f/(e - 1.f)) + rho1*(pave - pt);
    bool ind1 = !ind0;
    if (t > 0.f && ind1) pmin = pave;
    if (t < 0.f && ind1) pmax = pave;
    ind0 = ind0 || (t == 0.f && ind1);
    if (!ind0) pave = 0.5f*(pmin + pmax);
  }
  float pn = ind0i ? (pt - K0/rho1) : pave;
  phi_out[i] = pn;
  u1_out[i]  = u1[i] + pn - fp;
}

// =============================================================================
//                        Z-update: MFMA conv pipeline
// =============================================================================
#define CONV_R 4
__global__ __launch_bounds__(256, 4) void k_conv(const unsigned short* __restrict__ inCL,
                                                 const unsigned short* __restrict__ Aprep,
                                                 unsigned short* __restrict__ outCL,
                                                 float* __restrict__ part,
                                                 int mode,
                                                 const float* __restrict__ scsh,
                                                 const float* __restrict__ thrp) {
  __shared__ unsigned short tile[6*66*32];
  __shared__ float sred[4][16][2];
  int tid = threadIdx.x;
  int bx = blockIdx.x, by = blockIdx.y, bz = blockIdx.z;
  int w0 = bx*64, h0 = by*CONV_R;

  for (int idx = tid; idx < 6*264; idx += 256) {
    int lrow = idx/264, rem = idx - lrow*264;
    int lcol = rem >> 2, m = rem & 3;
    int grow = h0 - 1 + lrow, gcol = w0 - 1 + lcol;
    uint4 val = {0,0,0,0};
    if (grow >= 0 && grow < 256 && gcol >= 0 && gcol < 256) {
      uint4 raw = *(const uint4*)(inCL + (((size_t)(bz<<16) + (grow<<8) + gcol)<<5) + m*8);
      if (mode == 0) val = raw;
      else {
        unsigned short h8[8]; *(uint4*)h8 = raw;
        #pragma unroll
        for (int j = 0; j < 8; ++j) {
          float v = bf2f(h8[j]);
          int ic = m*8+j; v = v*scsh[ic] + scsh[32+ic]; v = v > 0.f ? v : 0.01f*v;
          h8[j] = f2bf(v);
        }
        val = *(uint4*)h8;
      }
    }
    *(uint4*)&tile[(size_t)idx*8] = val;
  }

  int lane = tid & 63, w = tid >> 6;
  int q = lane >> 4, ln = lane & 15;
  int ocH = w & 1, s0 = w >> 1;
  short8 afrag[9];
  #pragma unroll
  for (int t = 0; t < 9; ++t)
    afrag[t] = *(const short8*)(Aprep + ((t*32 + ocH*16 + ln)*32 + q*8));
  __syncthreads();

  float sacc[4] = {0,0,0,0}, s2acc[4] = {0,0,0,0};
  #pragma unroll
  for (int r = 0; r < CONV_R; ++r) {
    #pragma unroll
    for (int si = 0; si < 2; ++si) {
      int s = s0 + si*2;
      float4v acc = {0.f, 0.f, 0.f, 0.f};
      #pragma unroll
      for (int t = 0; t < 9; ++t) {
        int dy = t/3, dx = t - dy*3;
        int lrow = r + dy, lcol = s*16 + ln + dx;
        const short8 bfrag = *(const short8*)&tile[(lrow*66 + lcol)*32 + q*8];
        acc = __builtin_amdgcn_mfma_f32_16x16x32_bf16(afrag[t], bfrag, acc, 0, 0, 0);
      }
      int px = w0 + s*16 + ln, row = h0 + r;
      size_t obase = ((((size_t)(bz<<16) + (row<<8) + px))<<5) + ocH*16 + q*4;
      unsigned short o4[4];
      #pragma unroll
      for (int u = 0; u < 4; ++u) { o4[u] = f2bf(acc[u]); sacc[u] += acc[u]; s2acc[u] += acc[u]*acc[u]; }
      *(uint2*)(outCL + obase) = *(uint2*)o4;
    }
  }

  #pragma unroll
  for (int u = 0; u < 4; ++u) {
    float a = sacc[u], b2 = s2acc[u];
    #pragma unroll
    for (int mq = 1; mq < 16; mq <<= 1) { a += __shfl_xor(a, mq); b2 += __shfl_xor(b2, mq); }
    if (ln == 0) { sred[w][q*4+u][0] = a; sred[w][q*4+u][1] = b2; }
  }
  __syncthreads();
  if (tid < 64) {
    int ocH2 = tid >> 5, i16 = (tid >> 1) & 15, st = tid & 1;
    float tot = sred[ocH2][i16][st] + sred[ocH2+2][i16][st];
    int oc = ocH2*16 + i16;
    int blk = ((bz<<6) + by)*4 + bx;
    part[(oc*2+st)*1024 + blk] = tot;
  }
}

// dual-branch conv over h1 (computed on the fly from zt, c2, SS1):
// branch T = soft-thresholded h1, branch R = raw h1.  h1cl kernel eliminated.
__global__ __launch_bounds__(256, 3) void k_conv35(const unsigned short* __restrict__ ztcl,
                                                   const unsigned short* __restrict__ c2,
                                                   const unsigned short* __restrict__ Aprep,
                                                   unsigned short* __restrict__ outT,
                                                   unsigned short* __restrict__ outR,
                                                   float* __restrict__ partT,
                                                   float* __restrict__ partR,
                                                   const float* __restrict__ ss1,
                                                   const float* __restrict__ thrp) {
  __shared__ unsigned short tileR[6*66*32];
  __shared__ unsigned short tileT[6*66*32];
  __shared__ float sredT[4][16][2];
  __shared__ float sredR[4][16][2];
  int tid = threadIdx.x;
  int bx = blockIdx.x, by = blockIdx.y, bz = blockIdx.z;
  int w0 = bx*64, h0 = by*CONV_R;
  float thr = thrp[0];

  for (int idx = tid; idx < 6*264; idx += 256) {
    int lrow = idx/264, rem = idx - lrow*264;
    int lcol = rem >> 2, m = rem & 3;
    int grow = h0 - 1 + lrow, gcol = w0 - 1 + lcol;
    uint4 rawv = {0,0,0,0}, thrv = {0,0,0,0};
    if (grow >= 0 && grow < 256 && gcol >= 0 && gcol < 256) {
      size_t gaddr = (((size_t)(bz<<16) + (grow<<8) + gcol)<<5) + m*8;
      uint4 az = *(const uint4*)(ztcl + gaddr);
      uint4 ac = *(const uint4*)(c2 + gaddr);
      unsigned short z8[8], cc8[8], h8[8], t8[8];
      *(uint4*)z8 = az; *(uint4*)cc8 = ac;
      #pragma unroll
      for (int j = 0; j < 8; ++j) {
        int ic = m*8 + j;
        float v = bf2f(z8[j]) + bf2f(cc8[j])*ss1[ic] + ss1[32+ic];
        v = v > 0.f ? v : 0.01f*v;
        h8[j] = f2bf(v);
        float hb = bf2f(h8[j]);          // match the old H1cl bf16 rounding exactly
        float s = fabsf(hb) - thr; s = s > 0.f ? s : 0.f;
        t8[j] = f2bf(copysignf(s, hb));
      }
      rawv = *(uint4*)h8;
      thrv = *(uint4*)t8;
    }
    *(uint4*)&tileR[(size_t)idx*8] = rawv;
    *(uint4*)&tileT[(size_t)idx*8] = thrv;
  }

  int lane = tid & 63, w = tid >> 6;
  int q = lane >> 4, ln = lane & 15;
  int ocH = w & 1, s0 = w >> 1;
  short8 afrag[9];
  #pragma unroll
  for (int t = 0; t < 9; ++t)
    afrag[t] = *(const short8*)(Aprep + ((t*32 + ocH*16 + ln)*32 + q*8));
  __syncthreads();

  float saT[4] = {0,0,0,0}, s2T[4] = {0,0,0,0};
  float saR[4] = {0,0,0,0}, s2R[4] = {0,0,0,0};
  #pragma unroll
  for (int r = 0; r < CONV_R; ++r) {
    #pragma unroll
    for (int si = 0; si < 2; ++si) {
      int s = s0 + si*2;
      float4v accT = {0.f,0.f,0.f,0.f}, accR = {0.f,0.f,0.f,0.f};
      #pragma unroll
      for (int t = 0; t < 9; ++t) {
        int dy = t/3, dx = t - dy*3;
        int lrow = r + dy, lcol = s*16 + ln + dx;
        size_t off = ((size_t)(lrow*66 + lcol))*32 + q*8;
        const short8 bT = *(const short8*)&tileT[off];
        accT = __builtin_amdgcn_mfma_f32_16x16x32_bf16(afrag[t], bT, accT, 0, 0, 0);
        const short8 bR = *(const short8*)&tileR[off];
        accR = __builtin_amdgcn_mfma_f32_16x16x32_bf16(afrag[t], bR, accR, 0, 0, 0);
      }
      int px = w0 + s*16 + ln, row = h0 + r;
      size_t obase = ((((size_t)(bz<<16) + (row<<8) + px))<<5) + ocH*16 + q*4;
      unsigned short oT[4], oR[4];
      #pragma unroll
      for (int u = 0; u < 4; ++u) {
        oT[u] = f2bf(accT[u]); saT[u] += accT[u]; s2T[u] += accT[u]*accT[u];
        oR[u] = f2bf(accR[u]); saR[u] += accR[u]; s2R[u] += accR[u]*accR[u];
      }
      *(uint2*)(outT + obase) = *(uint2*)oT;
      *(uint2*)(outR + obase) = *(uint2*)oR;
    }
  }

  #pragma unroll
  for (int u = 0; u < 4; ++u) {
    float aT = saT[u], bT2 = s2T[u], aR = saR[u], bR2 = s2R[u];
    #pragma unroll
    for (int mq = 1; mq < 16; mq <<= 1) {
      aT += __shfl_xor(aT, mq); bT2 += __shfl_xor(bT2, mq);
      aR += __shfl_xor(aR, mq); bR2 += __shfl_xor(bR2, mq);
    }
    if (ln == 0) {
      sredT[w][q*4+u][0] = aT; sredT[w][q*4+u][1] = bT2;
      sredR[w][q*4+u][0] = aR; sredR[w][q*4+u][1] = bR2;
    }
  }
  __syncthreads();
  if (tid < 64) {
    int ocH2 = tid >> 5, i16 = (tid >> 1) & 15, st = tid & 1;
    int oc = ocH2*16 + i16;
    int blk = ((bz<<6) + by)*4 + bx;
    partT[(oc*2+st)*1024 + blk] = sredT[ocH2][i16][st] + sredT[ocH2+2][i16][st];
    partR[(oc*2+st)*1024 + blk] = sredR[ocH2][i16][st] + sredR[ocH2+2][i16][st];
  }
}

// merged conv4+conv6: z<4 -> branch A; z>=4 -> branch B
__global__ __launch_bounds__(256, 4) void k_conv_pair(const unsigned short* __restrict__ inA,
                                                      const unsigned short* __restrict__ inB,
                                                      unsigned short* __restrict__ outA,
                                                      unsigned short* __restrict__ outB,
                                                      float* __restrict__ partA,
                                                      float* __restrict__ partB,
                                                      const float* __restrict__ ssA,
                                                      const float* __restrict__ ssB,
                                                      const unsigned short* __restrict__ Aprep) {
  __shared__ unsigned short tile[6*66*32];
  __shared__ float sred[4][16][2];
  int tid = threadIdx.x;
  int bx = blockIdx.x, by = blockIdx.y;
  int half = blockIdx.z >> 2, bz = blockIdx.z & 3;
  const unsigned short* inCL = half ? inB : inA;
  unsigned short* outCL = half ? outB : outA;
  const float* scsh = half ? ssB : ssA;
  float* part = half ? partB : partA;
  int w0 = bx*64, h0 = by*CONV_R;

  for (int idx = tid; idx < 6*264; idx += 256) {
    int lrow = idx/264, rem = idx - lrow*264;
    int lcol = rem >> 2, m = rem & 3;
    int grow = h0 - 1 + lrow, gcol = w0 - 1 + lcol;
    uint4 val = {0,0,0,0};
    if (grow >= 0 && grow < 256 && gcol >= 0 && gcol < 256) {
      uint4 raw = *(const uint4*)(inCL + (((size_t)(bz<<16) + (grow<<8) + gcol)<<5) + m*8);
      unsigned short h8[8]; *(uint4*)h8 = raw;
      #pragma unroll
      for (int j = 0; j < 8; ++j) {
        float v = bf2f(h8[j]);
        int ic = m*8+j; v = v*scsh[ic] + scsh[32+ic]; v = v > 0.f ? v : 0.01f*v;
        h8[j] = f2bf(v);
      }
      val = *(uint4*)h8;
    }
    *(uint4*)&tile[(size_t)idx*8] = val;
  }

  int lane = tid & 63, w = tid >> 6;
  int q = lane >> 4, ln = lane & 15;
  int ocH = w & 1, s0 = w >> 1;
  short8 afrag[9];
  #pragma unroll
  for (int t = 0; t < 9; ++t)
    afrag[t] = *(const short8*)(Aprep + ((t*32 + ocH*16 + ln)*32 + q*8));
  __syncthreads();

  float sacc[4] = {0,0,0,0}, s2acc[4] = {0,0,0,0};
  #pragma unroll
  for (int r = 0; r < CONV_R; ++r) {
    #pragma unroll
    for (int si = 0; si < 2; ++si) {
      int s = s0 + si*2;
      float4v acc = {0.f, 0.f, 0.f, 0.f};
      #pragma unroll
      for (int t = 0; t < 9; ++t) {
        int dy = t/3, dx = t - dy*3;
        int lrow = r + dy, lcol = s*16 + ln + dx;
        const short8 bfrag = *(const short8*)&tile[(lrow*66 + lcol)*32 + q*8];
        acc = __builtin_amdgcn_mfma_f32_16x16x32_bf16(afrag[t], bfrag, acc, 0, 0, 0);
      }
      int px = w0 + s*16 + ln, row = h0 + r;
      size_t obase = ((((size_t)(bz<<16) + (row<<8) + px))<<5) + ocH*16 + q*4;
      unsigned short o4[4];
      #pragma unroll
      for (int u = 0; u < 4; ++u) { o4[u] = f2bf(acc[u]); sacc[u] += acc[u]; s2acc[u] += acc[u]*acc[u]; }
      *(uint2*)(outCL + obase) = *(uint2*)o4;
    }
  }

  #pragma unroll
  for (int u = 0; u < 4; ++u) {
    float a = sacc[u], b2 = s2acc[u];
    #pragma unroll
    for (int mq = 1; mq < 16; mq <<= 1) { a += __shfl_xor(a, mq); b2 += __shfl_xor(b2, mq); }
    if (ln == 0) { sred[w][q*4+u][0] = a; sred[w][q*4+u][1] = b2; }
  }
  __syncthreads();
  if (tid < 64) {
    int ocH2 = tid >> 5, i16 = (tid >> 1) & 15, st = tid & 1;
    float tot = sred[ocH2][i16][st] + sred[ocH2+2][i16][st];
    int oc = ocH2*16 + i16;
    int blk = ((bz<<6) + by)*4 + bx;
    part[(oc*2+st)*1024 + blk] = tot;
  }
}

// parallel BN-stat finalize: one block per output channel
__global__ __launch_bounds__(256) void k_finstats2(const float* __restrict__ part,
                                                   const float* __restrict__ g,
                                                   const float* __restrict__ beta,
                                                   float* __restrict__ SS) {
  __shared__ float red[8];
  int oc = blockIdx.x, t = threadIdx.x;
  const float* ps = part + oc*2048;
  float s  = ps[t] + ps[t+256] + ps[t+512] + ps[t+768];
  float s2 = ps[1024+t] + ps[1280+t] + ps[1536+t] + ps[1792+t];
  #pragma unroll
  for (int m = 1; m < 64; m <<= 1) { s += __shfl_xor(s, m); s2 += __shfl_xor(s2, m); }
  if ((t & 63) == 0) { red[(t>>6)*2] = s; red[(t>>6)*2+1] = s2; }
  __syncthreads();
  if (t == 0) {
    float S  = red[0] + red[2] + red[4] + red[6];
    float S2 = red[1] + red[3] + red[5] + red[7];
    const float N = 262144.f;
    float mean = S / N;
    float var  = S2 / N - mean*mean;
    float sc = g[oc] * rsqrtf(var + 1e-5f);
    SS[oc] = sc; SS[32+oc] = beta[oc] - mean*sc;
  }
}

// dual variant: blocks 0-31 finalize pA -> SSa; 32-63 finalize pB -> SSc
__global__ __launch_bounds__(256) void k_finstats_dual(const float* __restrict__ pA,
                                                       const float* __restrict__ pB,
                                                       const float* __restrict__ g,
                                                       const float* __restrict__ beta,
                                                       float* __restrict__ SSa,
                                                       float* __restrict__ SSc) {
  __shared__ float red[8];
  int bxi = blockIdx.x;
  const float* part = bxi < 32 ? pA : pB;
  float* SS = bxi < 32 ? SSa : SSc;
  int oc = bxi & 31, t = threadIdx.x;
  const float* ps = part + oc*2048;
  float s  = ps[t] + ps[t+256] + ps[t+512] + ps[t+768];
  float s2 = ps[1024+t] + ps[1280+t] + ps[1536+t] + ps[1792+t];
  #pragma unroll
  for (int m = 1; m < 64; m <<= 1) { s += __shfl_xor(s, m); s2 += __shfl_xor(s2, m); }
  if ((t & 63) == 0) { red[(t>>6)*2] = s; red[(t>>6)*2+1] = s2; }
  __syncthreads();
  if (t == 0) {
    float S  = red[0] + red[2] + red[4] + red[6];
    float S2 = red[1] + red[3] + red[5] + red[7];
    const float N = 262144.f;
    float mean = S / N;
    float var  = S2 / N - mean*mean;
    float sc = g[oc] * rsqrtf(var + 1e-5f);
    SS[oc] = sc; SS[32+oc] = beta[oc] - mean*sc;
  }
}

// fused finals: z, u2_next, sym (planar fp32).  h1 recomputed from zt+c2;
// u2_next = z_next + zt - 2*x  (u2 = zt - x), so the u2 read is eliminated.
__global__ __launch_bounds__(256) void k_finalAB(const unsigned short* __restrict__ ztcl,
                                                 const unsigned short* __restrict__ c2,
                                                 const unsigned short* __restrict__ c4,
                                                 const unsigned short* __restrict__ c6,
                                                 const float* __restrict__ SS1,
                                                 const float* __restrict__ SS4,
                                                 const float* __restrict__ SS6,
                                                 const float* __restrict__ thrp,
                                                 const float* __restrict__ x,
                                                 float* __restrict__ zout,
                                                 float* __restrict__ u2out,
                                                 float* __restrict__ symout) {
  __shared__ float zT[32*66];
  __shared__ float uT[32*66];
  __shared__ float sT[32*66];
  int tid = threadIdx.x;
  size_t b = blockIdx.y;
  int px0 = blockIdx.x*64;
  float thr = thrp[0];
  int px = tid >> 2, cg = tid & 3;
  size_t cbase = ((((b<<16) + px0 + px))<<5) + cg*8;
  uint4 za  = *(const uint4*)(ztcl + cbase);
  uint4 c2a = *(const uint4*)(c2 + cbase);
  uint4 c4a = *(const uint4*)(c4 + cbase);
  uint4 c6a = *(const uint4*)(c6 + cbase);
  unsigned short zs[8], c2s[8], c4s[8], c6s[8];
  *(uint4*)zs = za; *(uint4*)c2s = c2a; *(uint4*)c4s = c4a; *(uint4*)c6s = c6a;
  #pragma unroll
  for (int j = 0; j < 8; ++j) {
    int c = cg*8+j;
    float ztv = bf2f(zs[j]);
    float h0 = ztv + bf2f(c2s[j])*SS1[c] + SS1[32+c];
    h0 = h0 > 0.f ? h0 : 0.01f*h0;
    float hv = bf2f(f2bf(h0));           // match old H1cl bf16 rounding exactly
    float s = fabsf(hv) - thr; s = s > 0.f ? s : 0.f;
    float th = copysignf(s, hv);
    float zv = th + bf2f(c4s[j])*SS4[c] + SS4[32+c];
    zv = zv > 0.f ? zv : 0.01f*zv;
    float xv = hv + bf2f(c6s[j])*SS6[c] + SS6[32+c];
    xv = xv > 0.f ? xv : 0.01f*xv;
    zT[c*66 + px] = zv;
    uT[c*66 + px] = zv + ztv;
    sT[c*66 + px] = xv - ztv;
  }
  __syncthreads();
  #pragma unroll
  for (int i = 0; i < 2; ++i) {
    int ch = tid + i*256; int c = ch >> 4, p4 = (ch & 15)*4;
    size_t g = ((b*32 + c)<<16) + px0 + p4;
    float4 xv = *(const float4*)(x + g);
    float4 zv = { zT[c*66+p4], zT[c*66+p4+1], zT[c*66+p4+2], zT[c*66+p4+3] };
    float4 un = { uT[c*66+p4]   - 2.f*xv.x, uT[c*66+p4+1] - 2.f*xv.y,
                  uT[c*66+p4+2] - 2.f*xv.z, uT[c*66+p4+3] - 2.f*xv.w };
    float4 sv = { sT[c*66+p4], sT[c*66+p4+1], sT[c*66+p4+2], sT[c*66+p4+3] };
    *(float4*)(zout + g) = zv;
    *(float4*)(u2out + g) = un;
    *(float4*)(symout + g) = sv;
  }
}

// ================================================================================
extern "C" void kernel_launch(void* const* d_in, const int* in_sizes, int n_in,
                              void* d_out, int out_size, void* d_ws, size_t ws_size,
                              hipStream_t stream) {
  const float* phi  = (const float*)d_in[1];
  const float* z    = (const float*)d_in[2];
  const float* u1   = (const float*)d_in[3];
  const float* u2   = (const float*)d_in[4];
  const float* otr  = (const float*)d_in[5];
  const float* oti  = (const float*)d_in[6];
  const int*   K1   = (const int*)d_in[7];
  const float* rho1 = (const float*)d_in[8];
  const float* rho2 = (const float*)d_in[9];
  const float* sthr = (const float*)d_in[10];
  const float* w1a = (const float*)d_in[11];
  const float* g1a = (const float*)d_in[12];
  const float* b1a = (const float*)d_in[13];
  const float* w1b = (const float*)d_in[14];
  const float* g1b = (const float*)d_in[15];
  const float* b1b = (const float*)d_in[16];
  const float* w2a = (const float*)d_in[17];
  const float* g2a = (const float*)d_in[18];
  const float* b2a = (const float*)d_in[19];
  const float* w2b = (const float*)d_in[20];
  const float* g2b = (const float*)d_in[21];
  const float* b2b = (const float*)d_in[22];

  float* out = (float*)d_out;
  float* x_out   = out;                 // [B,D,H,W]
  float* phi_out = out + 8388608;
  float* z_out   = out + 8650752;
  float* u1_out  = out + 17039360;
  float* u2_out  = out + 17301504;
  float* sym_out = out + 25690112;

  char* ws = (char*)d_ws;
  cplx*  P     = (cplx*)ws;                          // 33.5 MB packed fwd spectrum
  cplx*  XS    = (cplx*)(ws + 67108864);             // 1 MB packed small spectrum (2 planes)
  cplx*  HFX   = (cplx*)(ws + 69206016);             // 2 MB row-inverted HF
  float* holo  = (float*)(ws + 71303168);            // 1 MB (71303168..72351744)
  float* partmm= (float*)(ws + 72351744);

  // Ap lives in the hole after XS (67108864+1MB = 68157440 .. 69206016)
  unsigned short* Ap    = (unsigned short*)(ws + 68157440);
  float*          part  = (float*)(ws + 71434240);            // inside dead holo
  float*          partB = (float*)(ws + 69206016);            // over dead HFX
  float*          SSb   = (float*)(ws + 71696384);            // inside dead holo
  unsigned short* ZTcl  = (unsigned short*)(ws + 33554432);   // 33554432..50331648
  unsigned short* C2cl  = (unsigned short*)(ws + 16777216);   // over dead P hi (must survive to finalAB)
  unsigned short* C4cl  = (unsigned short*)(ws + 0);          // over dead P lo
  unsigned short* C6cl  = (unsigned short*)(ws + 50331648);   // old H1cl slot (h1cl eliminated)
  unsigned short* C135a = (unsigned short*)z_out;             // scratch (dead pre-finalAB)
  unsigned short* C135b = (unsigned short*)((char*)z_out + 16777216);
  cplx* W2 = (cplx*)z_out;                                    // row-inverted Q planes

  // ---- X update (Fourier domain; Q kept on-chip) ----
  k_row_fwd_all <<<dim3(16, 67), 256, 0, stream>>>(z, u2, phi, u1, P, XS,
                                                   w1a, w1b, w2a, w2b, Ap);
  k_col_fwd_all <<<dim3(16, 66), 256, 0, stream>>>(P, XS);
  k_combine_inv <<<dim3(129, 4), 256, 0, stream>>>(P, XS, otr, oti, rho1, rho2, W2, HFX);
  k_col_inv_all <<<dim3(16, 68), 256, 0, stream>>>(W2, HFX, u2, x_out, ZTcl, holo, partmm);
  // ---- Phi update (min/max finalize folded in) ----
  k_bisect<<<1024, 256, 0, stream>>>(holo, partmm, u1, K1, rho1, phi_out, u1_out);

  // ---- Z update ----
  dim3 cg(4, 64, 4);
  k_conv<<<cg, 256, 0, stream>>>(ZTcl, Ap + 0,      C135a, part, 0, SSb,     sthr);
  k_finstats2<<<32, 256, 0, stream>>>(part, g1a, b1a, SSb + 0);
  k_conv<<<cg, 256, 0, stream>>>(C135a, Ap + 9216,  C2cl,  part, 1, SSb + 0, sthr);
  k_finstats2<<<32, 256, 0, stream>>>(part, g1b, b1b, SSb + 64);

  // conv3+conv5 with on-the-fly h1 (no h1cl staging kernel)
  k_conv35<<<cg, 256, 0, stream>>>(ZTcl, C2cl, Ap + 18432, C135a, C135b,
                                   part, partB, SSb + 64, sthr);
  k_finstats_dual<<<64, 256, 0, stream>>>(part, partB, g2a, b2a, SSb + 128, SSb + 256);
  k_conv_pair<<<dim3(4, 64, 8), 256, 0, stream>>>(C135a, C135b, C4cl, C6cl,
                                                  part, partB, SSb + 128, SSb + 256,
                                                  Ap + 27648);
  k_finstats_dual<<<64, 256, 0, stream>>>(part, partB, g2b, b2b, SSb + 192, SSb + 320);

  k_finalAB<<<dim3(1024, 4), 256, 0, stream>>>(ZTcl, C2cl, C4cl, C6cl,
                                               SSb + 64, SSb + 192, SSb + 320, sthr,
                                               x_out, z_out, u2_out, sym_out);
}